// Round 15
// baseline (543.766 us; speedup 1.0000x reference)
//
#include <hip/hip_runtime.h>
#include <hip/hip_fp16.h>
#include <math.h>
#include <type_traits>

#define N_NODES 50000
#define E_EDGES 1600000
#define TAU     0.5f
#define BN_EPS  1e-5f
#define SBSH    9                        // 512 dst nodes per super-bucket
#define NSB     ((N_NODES + 511) >> 9)   // 98 super-buckets
#define NSUBL   8                        // staging sub-lists (spread cursor LINES)
#define SUBCAP  2560                     // entries per sub-list (mean 2048 + >10 sigma)
#define BINCAP  48                       // LDS bin capacity (mean 10.4, +11 sigma)
#define EPB     1024                     // edges per scatter block
#define SCGRID  ((E_EDGES + EPB - 1) / EPB)
#define BSTR    16                       // cursor stride in ints (64B/line)

typedef _Float16 f16x8 __attribute__((ext_vector_type(8)));
typedef float    f32x4 __attribute__((ext_vector_type(4)));

__device__ __forceinline__ float dot8h(int4 a, int4 b) {
  const __half2* ah = (const __half2*)&a;
  const __half2* bh = (const __half2*)&b;
  float acc = 0.0f;
  #pragma unroll
  for (int q = 0; q < 4; ++q) {
    float2 fa = __half22float2(ah[q]);
    float2 fb = __half22float2(bh[q]);
    acc = fmaf(fa.x, fb.x, acc);
    acc = fmaf(fa.y, fb.y, acc);
  }
  return acc;
}

// ---------------------------------------------------------------------------
// 1) normalized fp16 features
__global__ __launch_bounds__(256) void xn_norm(
    const float* __restrict__ x, __half* __restrict__ xn, int n) {
  int wid  = (int)((blockIdx.x * blockDim.x + threadIdx.x) >> 6);
  int lane = threadIdx.x & 63;
  if (wid >= n) return;
  float2 v = ((const float2*)(x + (size_t)wid * 128))[lane];
  float s = v.x * v.x + v.y * v.y;
  #pragma unroll
  for (int off = 32; off; off >>= 1) s += __shfl_xor(s, off);
  float inv = 1.0f / (sqrtf(s) + 1e-12f);
  ((__half2*)(xn + (size_t)wid * 128))[lane] =
      __floats2half2_rn(v.x * inv, v.y * inv);
}

// ---------------------------------------------------------------------------
// 2a) LDS-binned scatter (unchanged from R14)
__global__ __launch_bounds__(256) void scatter_sb(
    const int* __restrict__ src, const int* __restrict__ dst,
    int* __restrict__ gc, unsigned* __restrict__ staging,
    int* __restrict__ ocnt, unsigned* __restrict__ ostage, int e) {
  __shared__ unsigned bins[NSB][BINCAP];
  __shared__ int bcount[NSB];
  const int tid  = threadIdx.x;
  const int wv   = tid >> 6;
  const int lane = tid & 63;
  const int sl   = blockIdx.x & (NSUBL - 1);
  for (int i = tid; i < NSB; i += 256) bcount[i] = 0;
  __syncthreads();

  int base = blockIdx.x * EPB;
  int bend = min(base + EPB, e);
  for (int i = base + tid; i < bend; i += 256) {
    int d = dst[i], s = src[i];
    int sb = d >> SBSH;
    int pos = atomicAdd(&bcount[sb], 1);
    if (pos < BINCAP) {
      bins[sb][pos] = (unsigned)s | ((unsigned)(d & 511) << 16);
    } else {
      int op = atomicAdd(ocnt, 1);
      ostage[op] = (unsigned)s | ((unsigned)d << 16);   // full dst
    }
  }
  __syncthreads();

  for (int sb = wv; sb < NSB; sb += 4) {
    int cnt = min(bcount[sb], BINCAP);
    if (cnt > 0) {
      int cell = sb * NSUBL + sl;
      int gbase = 0;
      if (lane == 0) gbase = atomicAdd(&gc[cell * BSTR], cnt);
      gbase = __shfl(gbase, 0);
      if (gbase + cnt <= SUBCAP) {
        if (lane < cnt)
          staging[(size_t)cell * SUBCAP + gbase + lane] = bins[sb][lane];
      } else if (lane < cnt) {
        unsigned u = bins[sb][lane];
        int op = atomicAdd(ocnt, 1);
        ostage[op] = (u & 0xFFFFu) | ((unsigned)((sb << SBSH) | (u >> 16)) << 16);
      }
    }
  }
}

// ---------------------------------------------------------------------------
// 2b) per-SB LDS histogram over the 8 sub-lists -> deg + SB total
__global__ __launch_bounds__(256) void hist_sb(
    const unsigned* __restrict__ staging, const int* __restrict__ gc,
    int* __restrict__ deg, int* __restrict__ sbsum, int n) {
  __shared__ int h[512];
  __shared__ int wt[4];
  int sb = blockIdx.x;
  for (int i = threadIdx.x; i < 512; i += 256) h[i] = 0;
  __syncthreads();
  for (int s = 0; s < NSUBL; ++s) {
    int cell = sb * NSUBL + s;
    int m = min(gc[cell * BSTR], SUBCAP);
    for (int i = threadIdx.x; i < m; i += 256)
      atomicAdd(&h[(staging[(size_t)cell * SUBCAP + i] >> 16) & 511], 1);
  }
  __syncthreads();
  int d0 = sb << SBSH;
  for (int i = threadIdx.x; i < 512; i += 256)
    if (d0 + i < n) deg[d0 + i] = h[i];
  int t = h[threadIdx.x] + h[threadIdx.x + 256];
  #pragma unroll
  for (int off = 32; off; off >>= 1) t += __shfl_xor(t, off);
  if ((threadIdx.x & 63) == 0) wt[threadIdx.x >> 6] = t;
  __syncthreads();
  if (threadIdx.x == 0) sbsum[sb] = wt[0] + wt[1] + wt[2] + wt[3];
}

// ---------------------------------------------------------------------------
// 2b') overflow patch (no-op when ocnt==0)
__global__ __launch_bounds__(256) void overflow_deg(
    const unsigned* __restrict__ ostage, const int* __restrict__ ocnt,
    int* __restrict__ deg, int* __restrict__ sbsum) {
  int m = *ocnt;
  for (int i = blockIdx.x * blockDim.x + threadIdx.x; i < m;
       i += gridDim.x * blockDim.x) {
    int d = (int)(ostage[i] >> 16);
    atomicAdd(&deg[d], 1);
    atomicAdd(&sbsum[d >> SBSH], 1);
  }
}

// ---------------------------------------------------------------------------
// 3a) exclusive scan over the 98 SB sums
__global__ void scan_sb(const int* __restrict__ sbsum, int* __restrict__ sbbase,
                        int* __restrict__ rowptr, int n) {
  __shared__ int part[128];
  int t = (int)threadIdx.x;
  int v = (t < NSB) ? sbsum[t] : 0;
  part[t] = v;
  __syncthreads();
  for (int off = 1; off < 128; off <<= 1) {
    int u = (t >= off) ? part[t - off] : 0;
    __syncthreads();
    part[t] += u;
    __syncthreads();
  }
  if (t < NSB) sbbase[t] = part[t] - v;
  if (t == 127) rowptr[n] = part[127];
}

// ---------------------------------------------------------------------------
// 3b) rowptr within SB: 512-element block scan (2 per thread)
__global__ __launch_bounds__(256) void rowptr_sb(
    const int* __restrict__ deg, const int* __restrict__ sbbase,
    int* __restrict__ rowptr, int n) {
  __shared__ int part[256];
  int sb = blockIdx.x;
  int d0 = sb << SBSH;
  int t = (int)threadIdx.x;
  int e0 = d0 + 2 * t;
  int v0 = (e0 < n) ? deg[e0] : 0;
  int v1 = (e0 + 1 < n) ? deg[e0 + 1] : 0;
  int s = v0 + v1;
  part[t] = s;
  __syncthreads();
  for (int off = 1; off < 256; off <<= 1) {
    int u = (t >= off) ? part[t - off] : 0;
    __syncthreads();
    part[t] += u;
    __syncthreads();
  }
  int ex = part[t] - s + sbbase[sb];
  if (e0 < n) rowptr[e0] = ex;
  if (e0 + 1 < n) rowptr[e0 + 1] = ex + v0;
}

// ---------------------------------------------------------------------------
// 2c) placement (unchanged)
__global__ __launch_bounds__(256) void place_sb(
    const unsigned* __restrict__ staging, const int* __restrict__ gc,
    const int* __restrict__ rowptr, unsigned short* __restrict__ csr16,
    int* __restrict__ gcur, int n) {
  __shared__ int cur[512];
  int sb = blockIdx.x;
  int d0 = sb << SBSH;
  for (int i = threadIdx.x; i < 512; i += 256)
    cur[i] = (d0 + i < n) ? rowptr[d0 + i] : 0;
  __syncthreads();
  for (int s = 0; s < NSUBL; ++s) {
    int cell = sb * NSUBL + s;
    int m = min(gc[cell * BSTR], SUBCAP);
    for (int i = threadIdx.x; i < m; i += 256) {
      unsigned u = staging[(size_t)cell * SUBCAP + i];
      int j = (u >> 16) & 511;
      int pos = atomicAdd(&cur[j], 1);
      csr16[pos] = (unsigned short)(u & 0xFFFFu);
    }
  }
  __syncthreads();
  for (int i = threadIdx.x; i < 512; i += 256)
    if (d0 + i < n) gcur[d0 + i] = cur[i];
}

// ---------------------------------------------------------------------------
// 2c') overflow placement (no-op when ocnt==0)
__global__ __launch_bounds__(256) void overflow_place(
    const unsigned* __restrict__ ostage, const int* __restrict__ ocnt,
    int* __restrict__ gcur, unsigned short* __restrict__ csr16) {
  int m = *ocnt;
  for (int i = blockIdx.x * blockDim.x + threadIdx.x; i < m;
       i += gridDim.x * blockDim.x) {
    unsigned u = ostage[i];
    int d = (int)(u >> 16);
    int pos = atomicAdd(&gcur[d], 1);
    csr16[pos] = (unsigned short)(u & 0xFFFFu);
  }
}

// ---------------------------------------------------------------------------
// 4) edge weights, dst-ordered: 8 edges in flight per wave (8 lanes/edge,
// 32 B/lane = 2 x int4). dst row cached in 2 regs; 3-step group reduce.
__global__ __launch_bounds__(256) void edge_weights(
    const __half* __restrict__ xn, const int* __restrict__ rowptr,
    const unsigned short* __restrict__ csr_src16,
    unsigned* __restrict__ csrp, float* __restrict__ denom, int n) {
  int wid  = (int)((blockIdx.x * blockDim.x + threadIdx.x) >> 6);
  int lane = threadIdx.x & 63;
  if (wid >= n) return;
  int grp = lane >> 3;       // edge slot 0..7
  int sub = lane & 7;        // 16-dim slice
  int beg = rowptr[wid], end = rowptr[wid + 1];
  const int4* xdp = (const int4*)(xn + (size_t)wid * 128);
  int4 xd0 = xdp[sub], xd1 = xdp[sub + 8];
  float wsum = 0.0f;

  for (int base = beg; base < end; base += 64) {
    int m = min(64, end - base);
    int sv = (lane < m) ? (int)csr_src16[base + lane] : 0;
    int iters = (m + 7) >> 3;
    #pragma unroll 2
    for (int q = 0; q < iters; ++q) {
      int ei = q * 8 + grp;
      int s = __shfl(sv, ei);
      const int4* xsp = (const int4*)(xn + (size_t)s * 128);
      int4 xs0 = xsp[sub], xs1 = xsp[sub + 8];
      float dp = dot8h(xs0, xd0) + dot8h(xs1, xd1);
      dp += __shfl_xor(dp, 1);
      dp += __shfl_xor(dp, 2);
      dp += __shfl_xor(dp, 4);
      bool valid = ei < m;
      float w = valid ? __expf(dp * (1.0f / TAU)) : 0.0f;
      wsum += w;
      if (valid && sub == 0) {
        unsigned w16 = (unsigned)__half_as_ushort(__float2half_rn(w));
        csrp[base + ei] = (unsigned)s | (w16 << 16);
      }
    }
  }
  // wsum uniform within each 8-lane group; combine the 8 groups
  wsum += __shfl_xor(wsum, 8);
  wsum += __shfl_xor(wsum, 16);
  wsum += __shfl_xor(wsum, 32);
  if (lane == 0) denom[wid] = wsum;
}

// ---------------------------------------------------------------------------
// 5a) weight prepack (unchanged)
__global__ __launch_bounds__(256) void prep_weights(
    const float* __restrict__ Wn0, const float* __restrict__ Wr0,
    const float* __restrict__ Wn1, const float* __restrict__ Wr1,
    const float* __restrict__ Wn2, const float* __restrict__ Wr2,
    const float* __restrict__ cn0, const float* __restrict__ cr0,
    const float* __restrict__ cn1, const float* __restrict__ cr1,
    const float* __restrict__ cn2, const float* __restrict__ cr2,
    __half* __restrict__ WtN0, __half* __restrict__ WtR0,
    __half* __restrict__ WtN1, __half* __restrict__ WtR1,
    __half* __restrict__ WtN2, __half* __restrict__ WtR2,
    float* __restrict__ bias0, float* __restrict__ bias1,
    float* __restrict__ bias2) {
  int i = blockIdx.x * blockDim.x + threadIdx.x;
  const float* Ws[6] = {Wn0, Wr0, Wn1, Wr1, Wn2, Wr2};
  __half*     Wts[6] = {WtN0, WtR0, WtN1, WtR1, WtN2, WtR2};
  int seg = -1, off = 0;
  if (i < 65536)        { seg = i >> 14;               off = i & 16383; }
  else if (i < 81920)   { int j = i - 65536; seg = 4 + (j >> 13); off = j & 8191; }
  if (seg >= 0) {
    int DO = (seg < 4) ? 128 : 64;
    int c = off >> 7, k = off & 127;
    Wts[seg][off] = __float2half_rn(Ws[seg][(size_t)k * DO + c]);
  }
  if (i < 128) { bias0[i] = cn0[i] + cr0[i]; bias1[i] = cn1[i] + cr1[i]; }
  if (i < 64)  { bias2[i] = cn2[i] + cr2[i]; }
}

// ---------------------------------------------------------------------------
// 5b) dual MFMA GEMM (unchanged)
template <int DO, typename TIN>
__global__ __launch_bounds__(256) void gemm_dual_mfma(
    const TIN* __restrict__ H, const __half* __restrict__ WtN,
    const __half* __restrict__ WtR, const float* __restrict__ bias,
    __half* __restrict__ Y, __half* __restrict__ Z, int n) {
  constexpr int NT = DO / 16;
  const int lane  = threadIdx.x & 63;
  const int w     = threadIdx.x >> 6;
  const int row0  = blockIdx.x * 64 + w * 16;
  const int col16 = lane & 15;
  const int kgrp  = (lane >> 4) * 8;
  const size_t arow = (size_t)min(row0 + col16, n - 1);

  f32x4 acc[2][NT];
  #pragma unroll
  for (int m = 0; m < 2; ++m)
    #pragma unroll
    for (int t = 0; t < NT; ++t) acc[m][t] = (f32x4){0.f, 0.f, 0.f, 0.f};

  #pragma unroll
  for (int kc = 0; kc < 4; ++kc) {
    f16x8 a;
    if constexpr (std::is_same<TIN, float>::value) {
      const float* hp = H + arow * 128 + kc * 32 + kgrp;
      float4 f0 = *(const float4*)hp;
      float4 f1 = *(const float4*)(hp + 4);
      a[0] = (_Float16)f0.x; a[1] = (_Float16)f0.y;
      a[2] = (_Float16)f0.z; a[3] = (_Float16)f0.w;
      a[4] = (_Float16)f1.x; a[5] = (_Float16)f1.y;
      a[6] = (_Float16)f1.z; a[7] = (_Float16)f1.w;
    } else {
      a = *(const f16x8*)(H + arow * 128 + kc * 32 + kgrp);
    }
    const __half* pN = WtN + (size_t)col16 * 128 + kc * 32 + kgrp;
    const __half* pR = WtR + (size_t)col16 * 128 + kc * 32 + kgrp;
    #pragma unroll
    for (int t = 0; t < NT; ++t) {
      f16x8 b = *(const f16x8*)(pN + (size_t)t * 16 * 128);
      acc[0][t] = __builtin_amdgcn_mfma_f32_16x16x32_f16(a, b, acc[0][t], 0, 0, 0);
    }
    #pragma unroll
    for (int t = 0; t < NT; ++t) {
      f16x8 b = *(const f16x8*)(pR + (size_t)t * 16 * 128);
      acc[1][t] = __builtin_amdgcn_mfma_f32_16x16x32_f16(a, b, acc[1][t], 0, 0, 0);
    }
  }

  const int rbase = (lane >> 4) * 4;
  #pragma unroll
  for (int t = 0; t < NT; ++t) {
    int col = t * 16 + col16;
    int pidx = col >> 5, incol = col & 31;
    float bz = bias[col];
    #pragma unroll
    for (int j = 0; j < 4; ++j) {
      int row = row0 + rbase + j;
      if (row < n) {
        Y[((size_t)pidx * n + row) * 32 + incol] = __float2half_rn(acc[0][t][j]);
        Z[(size_t)row * DO + col] = __float2half_rn(acc[1][t][j] + bz);
      }
    }
  }
}

// ---------------------------------------------------------------------------
// 6) aggregation pass over ONE 32-channel plane: 16 edges in flight per wave
// (4 lanes/edge, int4 = 16 B = 8 channels per lane). Reduce xor 32..4;
// epilogue on lanes 0..3 (8 channels each).
template <bool DO_BN, bool HALF_OUT>
__global__ __launch_bounds__(256) void agg_pass(
    const __half* __restrict__ Yp, const __half* __restrict__ Zb,
    const int* __restrict__ rowptr, const unsigned* __restrict__ csrp,
    const float* __restrict__ denom,
    const float* __restrict__ g, const float* __restrict__ bb,
    const float* __restrict__ mm, const float* __restrict__ vv,
    void* __restrict__ outv, int dofull, int choff, int n) {
  int wid  = (int)((blockIdx.x * blockDim.x + threadIdx.x) >> 6);
  int lane = threadIdx.x & 63;
  if (wid >= n) return;
  int grp = lane >> 2;     // edge slot 0..15
  int sub = lane & 3;      // channel octet 0..3 (8 ch each)
  int beg = rowptr[wid], end = rowptr[wid + 1];
  float inv = 1.0f / (denom[wid] + 1e-16f);

  float a[8];
  #pragma unroll
  for (int k = 0; k < 8; ++k) a[k] = 0.0f;

  for (int base = beg; base < end; base += 64) {
    int m = min(64, end - base);
    unsigned pk = (lane < m) ? csrp[base + lane] : 0u;   // w=0 when inactive
    int iters = (m + 15) >> 4;
    #pragma unroll 4
    for (int q = 0; q < iters; ++q) {
      unsigned u = __shfl(pk, q * 16 + grp);
      int   s = (int)(u & 0xFFFFu);
      float w = __half2float(__ushort_as_half((unsigned short)(u >> 16)));
      int4 raw = ((const int4*)(Yp + (size_t)s * 32))[sub];
      const __half2* hh = (const __half2*)&raw;
      #pragma unroll
      for (int k = 0; k < 4; ++k) {
        float2 f = __half22float2(hh[k]);
        a[2 * k]     = fmaf(w, f.x, a[2 * k]);
        a[2 * k + 1] = fmaf(w, f.y, a[2 * k + 1]);
      }
    }
  }
  #pragma unroll
  for (int off = 32; off >= 4; off >>= 1) {
    #pragma unroll
    for (int k = 0; k < 8; ++k) a[k] += __shfl_xor(a[k], off);
  }

  if (lane < 4) {
    int c = choff + sub * 8;
    int4 zr = *(const int4*)(Zb + (size_t)wid * dofull + c);
    const __half2* zh = (const __half2*)&zr;
    float o[8];
    #pragma unroll
    for (int k = 0; k < 4; ++k) {
      float2 z = __half22float2(zh[k]);
      o[2 * k]     = fmaf(a[2 * k], inv, z.x);
      o[2 * k + 1] = fmaf(a[2 * k + 1], inv, z.y);
    }
    if constexpr (DO_BN) {
      #pragma unroll
      for (int k = 0; k < 8; ++k) {
        float sc = g[c + k] * rsqrtf(vv[c + k] + BN_EPS);
        o[k] = fmaxf(fmaf(o[k] - mm[c + k], sc, bb[c + k]), 0.0f);
      }
    }
    if constexpr (HALF_OUT) {
      __half2 p0 = __floats2half2_rn(o[0], o[1]);
      __half2 p1 = __floats2half2_rn(o[2], o[3]);
      __half2 p2 = __floats2half2_rn(o[4], o[5]);
      __half2 p3 = __floats2half2_rn(o[6], o[7]);
      int4 pk4;
      pk4.x = *(int*)&p0; pk4.y = *(int*)&p1;
      pk4.z = *(int*)&p2; pk4.w = *(int*)&p3;
      *(int4*)((__half*)outv + (size_t)wid * dofull + c) = pk4;
    } else {
      float* op = (float*)outv + (size_t)wid * dofull + c;
      ((float4*)op)[0] = make_float4(o[0], o[1], o[2], o[3]);
      ((float4*)op)[1] = make_float4(o[4], o[5], o[6], o[7]);
    }
  }
}

// ---------------------------------------------------------------------------
extern "C" void kernel_launch(void* const* d_in, const int* in_sizes, int n_in,
                              void* d_out, int out_size, void* d_ws, size_t ws_size,
                              hipStream_t stream) {
  const float* x   = (const float*)d_in[0];
  const int*   ei  = (const int*)d_in[1];
  const float* Wn0 = (const float*)d_in[2];
  const float* cn0 = (const float*)d_in[3];
  const float* Wr0 = (const float*)d_in[4];
  const float* cr0 = (const float*)d_in[5];
  const float* Wn1 = (const float*)d_in[6];
  const float* cn1 = (const float*)d_in[7];
  const float* Wr1 = (const float*)d_in[8];
  const float* cr1 = (const float*)d_in[9];
  const float* Wn2 = (const float*)d_in[10];
  const float* cn2 = (const float*)d_in[11];
  const float* Wr2 = (const float*)d_in[12];
  const float* cr2 = (const float*)d_in[13];
  const float* g0  = (const float*)d_in[14];
  const float* b0  = (const float*)d_in[15];
  const float* m0  = (const float*)d_in[16];
  const float* v0  = (const float*)d_in[17];
  const float* g1  = (const float*)d_in[18];
  const float* b1  = (const float*)d_in[19];
  const float* m1  = (const float*)d_in[20];
  const float* v1  = (const float*)d_in[21];

  const int* src = ei;
  const int* dst = ei + E_EDGES;

  char* p = (char*)d_ws;
  auto alloc = [&](size_t bytes) {
    char* r = p;
    p += (bytes + 255) & ~(size_t)255;
    return r;
  };
  __half*         P0      = (__half*)        alloc((size_t)N_NODES * 128 * 2);
  __half*         P1      = (__half*)        alloc((size_t)N_NODES * 128 * 2);
  __half*         A16     = (__half*)        alloc((size_t)N_NODES * 128 * 2);
  unsigned*       staging = (unsigned*)      alloc((size_t)NSB * NSUBL * SUBCAP * 4); // 8 MB
  int*            deg     = (int*)           alloc((size_t)N_NODES * 4);
  float*          denom   = (float*)         alloc((size_t)N_NODES * 4);
  int*            rowptr  = (int*)           alloc((size_t)(N_NODES + 1) * 4);
  int*            gcur    = (int*)           alloc((size_t)N_NODES * 4);
  int*            sbsum   = (int*)           alloc((size_t)NSB * 4);
  int*            sbbase  = (int*)           alloc((size_t)NSB * 4);
  int*            gc      = (int*)           alloc((size_t)(NSB * NSUBL * BSTR + 16) * 4);
  unsigned short* csrs16  = (unsigned short*)alloc((size_t)E_EDGES * 2);
  unsigned*       csrp    = (unsigned*)      alloc((size_t)E_EDGES * 4);
  __half*         WtN0    = (__half*)        alloc(128 * 128 * 2);
  __half*         WtR0    = (__half*)        alloc(128 * 128 * 2);
  __half*         WtN1    = (__half*)        alloc(128 * 128 * 2);
  __half*         WtR1    = (__half*)        alloc(128 * 128 * 2);
  __half*         WtN2    = (__half*)        alloc(64 * 128 * 2);
  __half*         WtR2    = (__half*)        alloc(64 * 128 * 2);
  float*          bias0   = (float*)         alloc(128 * 4);
  float*          bias1   = (float*)         alloc(128 * 4);
  float*          bias2   = (float*)         alloc(64 * 4);

  // overflow list aliases csrp (only written later by edge_weights; overflow
  // consumers all run before edge_weights)
  unsigned* ostage = (unsigned*)csrp;
  int*      ocnt   = gc + NSB * NSUBL * BSTR;   // covered by gc memset

  hipMemsetAsync(gc, 0, (size_t)(NSB * NSUBL * BSTR + 16) * 4, stream);

  const int node_grid = (N_NODES * 64 + 255) / 256;

  xn_norm<<<node_grid, 256, 0, stream>>>(x, P0, N_NODES);
  prep_weights<<<320, 256, 0, stream>>>(Wn0, Wr0, Wn1, Wr1, Wn2, Wr2,
                                        cn0, cr0, cn1, cr1, cn2, cr2,
                                        WtN0, WtR0, WtN1, WtR1, WtN2, WtR2,
                                        bias0, bias1, bias2);
  scatter_sb<<<SCGRID, 256, 0, stream>>>(src, dst, gc, staging, ocnt, ostage, E_EDGES);
  hist_sb<<<NSB, 256, 0, stream>>>(staging, gc, deg, sbsum, N_NODES);
  overflow_deg<<<64, 256, 0, stream>>>(ostage, ocnt, deg, sbsum);
  scan_sb<<<1, 128, 0, stream>>>(sbsum, sbbase, rowptr, N_NODES);
  rowptr_sb<<<NSB, 256, 0, stream>>>(deg, sbbase, rowptr, N_NODES);
  place_sb<<<NSB, 256, 0, stream>>>(staging, gc, rowptr, csrs16, gcur, N_NODES);
  overflow_place<<<64, 256, 0, stream>>>(ostage, ocnt, gcur, csrs16);
  edge_weights<<<node_grid, 256, 0, stream>>>(P0, rowptr, csrs16, csrp, denom, N_NODES);

  const int gemm_grid = (N_NODES + 63) / 64;

  // layer 0
  gemm_dual_mfma<128, float><<<gemm_grid, 256, 0, stream>>>(
      x, WtN0, WtR0, bias0, P0, P1, N_NODES);
  for (int pass = 0; pass < 4; ++pass)
    agg_pass<true, true><<<node_grid, 256, 0, stream>>>(
        P0 + (size_t)pass * N_NODES * 32, P1, rowptr, csrp, denom,
        g0, b0, m0, v0, A16, 128, pass * 32, N_NODES);

  // layer 1
  gemm_dual_mfma<128, __half><<<gemm_grid, 256, 0, stream>>>(
      A16, WtN1, WtR1, bias1, P0, P1, N_NODES);
  for (int pass = 0; pass < 4; ++pass)
    agg_pass<true, true><<<node_grid, 256, 0, stream>>>(
        P0 + (size_t)pass * N_NODES * 32, P1, rowptr, csrp, denom,
        g1, b1, m1, v1, A16, 128, pass * 32, N_NODES);

  // layer 2
  gemm_dual_mfma<64, __half><<<gemm_grid, 256, 0, stream>>>(
      A16, WtN2, WtR2, bias2, P0, P1, N_NODES);
  for (int pass = 0; pass < 2; ++pass)
    agg_pass<false, false><<<node_grid, 256, 0, stream>>>(
        P0 + (size_t)pass * N_NODES * 32, P1, rowptr, csrp, denom,
        nullptr, nullptr, nullptr, nullptr, d_out, 64, pass * 32, N_NODES);
}

// Round 16
// 525.791 us; speedup vs baseline: 1.0342x; 1.0342x over previous
//
#include <hip/hip_runtime.h>
#include <hip/hip_fp16.h>
#include <math.h>
#include <type_traits>

#define N_NODES 50000
#define E_EDGES 1600000
#define TAU     0.5f
#define BN_EPS  1e-5f
#define SBSH    9                        // 512 dst nodes per super-bucket
#define NSB     ((N_NODES + 511) >> 9)   // 98 super-buckets
#define NSUBL   8                        // staging sub-lists (spread cursor LINES)
#define SUBCAP  2560                     // entries per sub-list (mean 2048 + >10 sigma)
#define BINCAP  48                       // LDS bin capacity (mean 10.4, +11 sigma)
#define EPB     1024                     // edges per scatter block
#define SCGRID  ((E_EDGES + EPB - 1) / EPB)
#define BSTR    16                       // cursor stride in ints (64B/line)

typedef _Float16 f16x8 __attribute__((ext_vector_type(8)));
typedef float    f32x4 __attribute__((ext_vector_type(4)));

__device__ __forceinline__ float dot8h(int4 a, int4 b) {
  const __half2* ah = (const __half2*)&a;
  const __half2* bh = (const __half2*)&b;
  float acc = 0.0f;
  #pragma unroll
  for (int q = 0; q < 4; ++q) {
    float2 fa = __half22float2(ah[q]);
    float2 fb = __half22float2(bh[q]);
    acc = fmaf(fa.x, fb.x, acc);
    acc = fmaf(fa.y, fb.y, acc);
  }
  return acc;
}

// ---------------------------------------------------------------------------
// 1) normalized fp16 features
__global__ __launch_bounds__(256) void xn_norm(
    const float* __restrict__ x, __half* __restrict__ xn, int n) {
  int wid  = (int)((blockIdx.x * blockDim.x + threadIdx.x) >> 6);
  int lane = threadIdx.x & 63;
  if (wid >= n) return;
  float2 v = ((const float2*)(x + (size_t)wid * 128))[lane];
  float s = v.x * v.x + v.y * v.y;
  #pragma unroll
  for (int off = 32; off; off >>= 1) s += __shfl_xor(s, off);
  float inv = 1.0f / (sqrtf(s) + 1e-12f);
  ((__half2*)(xn + (size_t)wid * 128))[lane] =
      __floats2half2_rn(v.x * inv, v.y * inv);
}

// ---------------------------------------------------------------------------
// 2a) LDS-binned scatter (unchanged from R15)
__global__ __launch_bounds__(256) void scatter_sb(
    const int* __restrict__ src, const int* __restrict__ dst,
    int* __restrict__ gc, unsigned* __restrict__ staging,
    int* __restrict__ ocnt, unsigned* __restrict__ ostage, int e) {
  __shared__ unsigned bins[NSB][BINCAP];
  __shared__ int bcount[NSB];
  const int tid  = threadIdx.x;
  const int wv   = tid >> 6;
  const int lane = tid & 63;
  const int sl   = blockIdx.x & (NSUBL - 1);
  for (int i = tid; i < NSB; i += 256) bcount[i] = 0;
  __syncthreads();

  int base = blockIdx.x * EPB;
  int bend = min(base + EPB, e);
  for (int i = base + tid; i < bend; i += 256) {
    int d = dst[i], s = src[i];
    int sb = d >> SBSH;
    int pos = atomicAdd(&bcount[sb], 1);
    if (pos < BINCAP) {
      bins[sb][pos] = (unsigned)s | ((unsigned)(d & 511) << 16);
    } else {
      int op = atomicAdd(ocnt, 1);
      ostage[op] = (unsigned)s | ((unsigned)d << 16);   // full dst
    }
  }
  __syncthreads();

  for (int sb = wv; sb < NSB; sb += 4) {
    int cnt = min(bcount[sb], BINCAP);
    if (cnt > 0) {
      int cell = sb * NSUBL + sl;
      int gbase = 0;
      if (lane == 0) gbase = atomicAdd(&gc[cell * BSTR], cnt);
      gbase = __shfl(gbase, 0);
      if (gbase + cnt <= SUBCAP) {
        if (lane < cnt)
          staging[(size_t)cell * SUBCAP + gbase + lane] = bins[sb][lane];
      } else if (lane < cnt) {
        unsigned u = bins[sb][lane];
        int op = atomicAdd(ocnt, 1);
        ostage[op] = (u & 0xFFFFu) | ((unsigned)((sb << SBSH) | (u >> 16)) << 16);
      }
    }
  }
}

// ---------------------------------------------------------------------------
// 2b) per-SB LDS histogram over the 8 sub-lists -> deg + SB total
__global__ __launch_bounds__(256) void hist_sb(
    const unsigned* __restrict__ staging, const int* __restrict__ gc,
    int* __restrict__ deg, int* __restrict__ sbsum, int n) {
  __shared__ int h[512];
  __shared__ int wt[4];
  int sb = blockIdx.x;
  for (int i = threadIdx.x; i < 512; i += 256) h[i] = 0;
  __syncthreads();
  for (int s = 0; s < NSUBL; ++s) {
    int cell = sb * NSUBL + s;
    int m = min(gc[cell * BSTR], SUBCAP);
    for (int i = threadIdx.x; i < m; i += 256)
      atomicAdd(&h[(staging[(size_t)cell * SUBCAP + i] >> 16) & 511], 1);
  }
  __syncthreads();
  int d0 = sb << SBSH;
  for (int i = threadIdx.x; i < 512; i += 256)
    if (d0 + i < n) deg[d0 + i] = h[i];
  int t = h[threadIdx.x] + h[threadIdx.x + 256];
  #pragma unroll
  for (int off = 32; off; off >>= 1) t += __shfl_xor(t, off);
  if ((threadIdx.x & 63) == 0) wt[threadIdx.x >> 6] = t;
  __syncthreads();
  if (threadIdx.x == 0) sbsum[sb] = wt[0] + wt[1] + wt[2] + wt[3];
}

// ---------------------------------------------------------------------------
// 2b') overflow patch (no-op when ocnt==0)
__global__ __launch_bounds__(256) void overflow_deg(
    const unsigned* __restrict__ ostage, const int* __restrict__ ocnt,
    int* __restrict__ deg, int* __restrict__ sbsum) {
  int m = *ocnt;
  for (int i = blockIdx.x * blockDim.x + threadIdx.x; i < m;
       i += gridDim.x * blockDim.x) {
    int d = (int)(ostage[i] >> 16);
    atomicAdd(&deg[d], 1);
    atomicAdd(&sbsum[d >> SBSH], 1);
  }
}

// ---------------------------------------------------------------------------
// 3a) exclusive scan over the 98 SB sums
__global__ void scan_sb(const int* __restrict__ sbsum, int* __restrict__ sbbase,
                        int* __restrict__ rowptr, int n) {
  __shared__ int part[128];
  int t = (int)threadIdx.x;
  int v = (t < NSB) ? sbsum[t] : 0;
  part[t] = v;
  __syncthreads();
  for (int off = 1; off < 128; off <<= 1) {
    int u = (t >= off) ? part[t - off] : 0;
    __syncthreads();
    part[t] += u;
    __syncthreads();
  }
  if (t < NSB) sbbase[t] = part[t] - v;
  if (t == 127) rowptr[n] = part[127];
}

// ---------------------------------------------------------------------------
// 3b) rowptr within SB: 512-element block scan (2 per thread)
__global__ __launch_bounds__(256) void rowptr_sb(
    const int* __restrict__ deg, const int* __restrict__ sbbase,
    int* __restrict__ rowptr, int n) {
  __shared__ int part[256];
  int sb = blockIdx.x;
  int d0 = sb << SBSH;
  int t = (int)threadIdx.x;
  int e0 = d0 + 2 * t;
  int v0 = (e0 < n) ? deg[e0] : 0;
  int v1 = (e0 + 1 < n) ? deg[e0 + 1] : 0;
  int s = v0 + v1;
  part[t] = s;
  __syncthreads();
  for (int off = 1; off < 256; off <<= 1) {
    int u = (t >= off) ? part[t - off] : 0;
    __syncthreads();
    part[t] += u;
    __syncthreads();
  }
  int ex = part[t] - s + sbbase[sb];
  if (e0 < n) rowptr[e0] = ex;
  if (e0 + 1 < n) rowptr[e0 + 1] = ex + v0;
}

// ---------------------------------------------------------------------------
// 2c) placement (unchanged)
__global__ __launch_bounds__(256) void place_sb(
    const unsigned* __restrict__ staging, const int* __restrict__ gc,
    const int* __restrict__ rowptr, unsigned short* __restrict__ csr16,
    int* __restrict__ gcur, int n) {
  __shared__ int cur[512];
  int sb = blockIdx.x;
  int d0 = sb << SBSH;
  for (int i = threadIdx.x; i < 512; i += 256)
    cur[i] = (d0 + i < n) ? rowptr[d0 + i] : 0;
  __syncthreads();
  for (int s = 0; s < NSUBL; ++s) {
    int cell = sb * NSUBL + s;
    int m = min(gc[cell * BSTR], SUBCAP);
    for (int i = threadIdx.x; i < m; i += 256) {
      unsigned u = staging[(size_t)cell * SUBCAP + i];
      int j = (u >> 16) & 511;
      int pos = atomicAdd(&cur[j], 1);
      csr16[pos] = (unsigned short)(u & 0xFFFFu);
    }
  }
  __syncthreads();
  for (int i = threadIdx.x; i < 512; i += 256)
    if (d0 + i < n) gcur[d0 + i] = cur[i];
}

// ---------------------------------------------------------------------------
// 2c') overflow placement (no-op when ocnt==0)
__global__ __launch_bounds__(256) void overflow_place(
    const unsigned* __restrict__ ostage, const int* __restrict__ ocnt,
    int* __restrict__ gcur, unsigned short* __restrict__ csr16) {
  int m = *ocnt;
  for (int i = blockIdx.x * blockDim.x + threadIdx.x; i < m;
       i += gridDim.x * blockDim.x) {
    unsigned u = ostage[i];
    int d = (int)(u >> 16);
    int pos = atomicAdd(&gcur[d], 1);
    csr16[pos] = (unsigned short)(u & 0xFFFFu);
  }
}

// ---------------------------------------------------------------------------
// 4) edge weights, dst-ordered (unchanged from R15)
__global__ __launch_bounds__(256) void edge_weights(
    const __half* __restrict__ xn, const int* __restrict__ rowptr,
    const unsigned short* __restrict__ csr_src16,
    unsigned* __restrict__ csrp, float* __restrict__ denom, int n) {
  int wid  = (int)((blockIdx.x * blockDim.x + threadIdx.x) >> 6);
  int lane = threadIdx.x & 63;
  if (wid >= n) return;
  int grp = lane >> 3;       // edge slot 0..7
  int sub = lane & 7;        // 16-dim slice
  int beg = rowptr[wid], end = rowptr[wid + 1];
  const int4* xdp = (const int4*)(xn + (size_t)wid * 128);
  int4 xd0 = xdp[sub], xd1 = xdp[sub + 8];
  float wsum = 0.0f;

  for (int base = beg; base < end; base += 64) {
    int m = min(64, end - base);
    int sv = (lane < m) ? (int)csr_src16[base + lane] : 0;
    int iters = (m + 7) >> 3;
    #pragma unroll 2
    for (int q = 0; q < iters; ++q) {
      int ei = q * 8 + grp;
      int s = __shfl(sv, ei);
      const int4* xsp = (const int4*)(xn + (size_t)s * 128);
      int4 xs0 = xsp[sub], xs1 = xsp[sub + 8];
      float dp = dot8h(xs0, xd0) + dot8h(xs1, xd1);
      dp += __shfl_xor(dp, 1);
      dp += __shfl_xor(dp, 2);
      dp += __shfl_xor(dp, 4);
      bool valid = ei < m;
      float w = valid ? __expf(dp * (1.0f / TAU)) : 0.0f;
      wsum += w;
      if (valid && sub == 0) {
        unsigned w16 = (unsigned)__half_as_ushort(__float2half_rn(w));
        csrp[base + ei] = (unsigned)s | (w16 << 16);
      }
    }
  }
  wsum += __shfl_xor(wsum, 8);
  wsum += __shfl_xor(wsum, 16);
  wsum += __shfl_xor(wsum, 32);
  if (lane == 0) denom[wid] = wsum;
}

// ---------------------------------------------------------------------------
// 5a) weight prepack in MFMA FRAGMENT ORDER:
// Wf[((t*4+kc)*64 + lane)*8 + j] = W[k][c] with t=c>>4, kc=k>>5,
// lane=(c&15)|(((k>>3)&3)<<4), j=k&7 -> a B-fragment load is 64 lanes
// reading 64 consecutive 8-half blocks = one contiguous 1KB coalesced read.
__global__ __launch_bounds__(256) void prep_weights(
    const float* __restrict__ Wn0, const float* __restrict__ Wr0,
    const float* __restrict__ Wn1, const float* __restrict__ Wr1,
    const float* __restrict__ Wn2, const float* __restrict__ Wr2,
    const float* __restrict__ cn0, const float* __restrict__ cr0,
    const float* __restrict__ cn1, const float* __restrict__ cr1,
    const float* __restrict__ cn2, const float* __restrict__ cr2,
    __half* __restrict__ WtN0, __half* __restrict__ WtR0,
    __half* __restrict__ WtN1, __half* __restrict__ WtR1,
    __half* __restrict__ WtN2, __half* __restrict__ WtR2,
    float* __restrict__ bias0, float* __restrict__ bias1,
    float* __restrict__ bias2) {
  int i = blockIdx.x * blockDim.x + threadIdx.x;
  const float* Ws[6] = {Wn0, Wr0, Wn1, Wr1, Wn2, Wr2};
  __half*     Wts[6] = {WtN0, WtR0, WtN1, WtR1, WtN2, WtR2};
  int seg = -1, off = 0;
  if (i < 65536)        { seg = i >> 14;               off = i & 16383; }
  else if (i < 81920)   { int j = i - 65536; seg = 4 + (j >> 13); off = j & 8191; }
  if (seg >= 0) {
    int DO = (seg < 4) ? 128 : 64;
    int c = off >> 7, k = off & 127;
    int t = c >> 4, kc = k >> 5, kgrp = (k >> 3) & 3, j = k & 7;
    int lane = (c & 15) | (kgrp << 4);
    int idx = (((t * 4 + kc) * 64 + lane) << 3) + j;
    Wts[seg][idx] = __float2half_rn(Ws[seg][(size_t)k * DO + c]);
  }
  if (i < 128) { bias0[i] = cn0[i] + cr0[i]; bias1[i] = cn1[i] + cr1[i]; }
  if (i < 64)  { bias2[i] = cn2[i] + cr2[i]; }
}

// ---------------------------------------------------------------------------
// 5b) dual MFMA GEMM: B fragments now from fragment-ordered Wf -> coalesced
// 1KB loads (was 64 scattered 16B requests per instruction = request-rate
// bound, MfmaUtil 2.3%). A-path/stores unchanged.
template <int DO, typename TIN>
__global__ __launch_bounds__(256) void gemm_dual_mfma(
    const TIN* __restrict__ H, const __half* __restrict__ WfN,
    const __half* __restrict__ WfR, const float* __restrict__ bias,
    __half* __restrict__ Y, __half* __restrict__ Z, int n) {
  constexpr int NT = DO / 16;
  const int lane  = threadIdx.x & 63;
  const int w     = threadIdx.x >> 6;
  const int row0  = blockIdx.x * 64 + w * 16;
  const int col16 = lane & 15;
  const int kgrp  = (lane >> 4) * 8;
  const size_t arow = (size_t)min(row0 + col16, n - 1);

  f32x4 acc[2][NT];
  #pragma unroll
  for (int m = 0; m < 2; ++m)
    #pragma unroll
    for (int t = 0; t < NT; ++t) acc[m][t] = (f32x4){0.f, 0.f, 0.f, 0.f};

  #pragma unroll
  for (int kc = 0; kc < 4; ++kc) {
    f16x8 a;
    if constexpr (std::is_same<TIN, float>::value) {
      const float* hp = H + arow * 128 + kc * 32 + kgrp;
      float4 f0 = *(const float4*)hp;
      float4 f1 = *(const float4*)(hp + 4);
      a[0] = (_Float16)f0.x; a[1] = (_Float16)f0.y;
      a[2] = (_Float16)f0.z; a[3] = (_Float16)f0.w;
      a[4] = (_Float16)f1.x; a[5] = (_Float16)f1.y;
      a[6] = (_Float16)f1.z; a[7] = (_Float16)f1.w;
    } else {
      a = *(const f16x8*)(H + arow * 128 + kc * 32 + kgrp);
    }
    // fragment-ordered weights: block index (t*4+kc)*64 + lane, 8 halves each
    const f16x8* bN = (const f16x8*)(WfN + ((size_t)(kc * 64 + lane) << 3));
    const f16x8* bR = (const f16x8*)(WfR + ((size_t)(kc * 64 + lane) << 3));
    #pragma unroll
    for (int t = 0; t < NT; ++t) {
      f16x8 b = bN[t * 256];
      acc[0][t] = __builtin_amdgcn_mfma_f32_16x16x32_f16(a, b, acc[0][t], 0, 0, 0);
    }
    #pragma unroll
    for (int t = 0; t < NT; ++t) {
      f16x8 b = bR[t * 256];
      acc[1][t] = __builtin_amdgcn_mfma_f32_16x16x32_f16(a, b, acc[1][t], 0, 0, 0);
    }
  }

  const int rbase = (lane >> 4) * 4;
  #pragma unroll
  for (int t = 0; t < NT; ++t) {
    int col = t * 16 + col16;
    int pidx = col >> 5, incol = col & 31;
    float bz = bias[col];
    #pragma unroll
    for (int j = 0; j < 4; ++j) {
      int row = row0 + rbase + j;
      if (row < n) {
        Y[((size_t)pidx * n + row) * 32 + incol] = __float2half_rn(acc[0][t][j]);
        Z[(size_t)row * DO + col] = __float2half_rn(acc[1][t][j] + bz);
      }
    }
  }
}

// ---------------------------------------------------------------------------
// 6) aggregation pass over ONE 32-channel plane (unchanged from R15)
template <bool DO_BN, bool HALF_OUT>
__global__ __launch_bounds__(256) void agg_pass(
    const __half* __restrict__ Yp, const __half* __restrict__ Zb,
    const int* __restrict__ rowptr, const unsigned* __restrict__ csrp,
    const float* __restrict__ denom,
    const float* __restrict__ g, const float* __restrict__ bb,
    const float* __restrict__ mm, const float* __restrict__ vv,
    void* __restrict__ outv, int dofull, int choff, int n) {
  int wid  = (int)((blockIdx.x * blockDim.x + threadIdx.x) >> 6);
  int lane = threadIdx.x & 63;
  if (wid >= n) return;
  int grp = lane >> 2;     // edge slot 0..15
  int sub = lane & 3;      // channel octet 0..3 (8 ch each)
  int beg = rowptr[wid], end = rowptr[wid + 1];
  float inv = 1.0f / (denom[wid] + 1e-16f);

  float a[8];
  #pragma unroll
  for (int k = 0; k < 8; ++k) a[k] = 0.0f;

  for (int base = beg; base < end; base += 64) {
    int m = min(64, end - base);
    unsigned pk = (lane < m) ? csrp[base + lane] : 0u;   // w=0 when inactive
    int iters = (m + 15) >> 4;
    #pragma unroll 4
    for (int q = 0; q < iters; ++q) {
      unsigned u = __shfl(pk, q * 16 + grp);
      int   s = (int)(u & 0xFFFFu);
      float w = __half2float(__ushort_as_half((unsigned short)(u >> 16)));
      int4 raw = ((const int4*)(Yp + (size_t)s * 32))[sub];
      const __half2* hh = (const __half2*)&raw;
      #pragma unroll
      for (int k = 0; k < 4; ++k) {
        float2 f = __half22float2(hh[k]);
        a[2 * k]     = fmaf(w, f.x, a[2 * k]);
        a[2 * k + 1] = fmaf(w, f.y, a[2 * k + 1]);
      }
    }
  }
  #pragma unroll
  for (int off = 32; off >= 4; off >>= 1) {
    #pragma unroll
    for (int k = 0; k < 8; ++k) a[k] += __shfl_xor(a[k], off);
  }

  if (lane < 4) {
    int c = choff + sub * 8;
    int4 zr = *(const int4*)(Zb + (size_t)wid * dofull + c);
    const __half2* zh = (const __half2*)&zr;
    float o[8];
    #pragma unroll
    for (int k = 0; k < 4; ++k) {
      float2 z = __half22float2(zh[k]);
      o[2 * k]     = fmaf(a[2 * k], inv, z.x);
      o[2 * k + 1] = fmaf(a[2 * k + 1], inv, z.y);
    }
    if constexpr (DO_BN) {
      #pragma unroll
      for (int k = 0; k < 8; ++k) {
        float sc = g[c + k] * rsqrtf(vv[c + k] + BN_EPS);
        o[k] = fmaxf(fmaf(o[k] - mm[c + k], sc, bb[c + k]), 0.0f);
      }
    }
    if constexpr (HALF_OUT) {
      __half2 p0 = __floats2half2_rn(o[0], o[1]);
      __half2 p1 = __floats2half2_rn(o[2], o[3]);
      __half2 p2 = __floats2half2_rn(o[4], o[5]);
      __half2 p3 = __floats2half2_rn(o[6], o[7]);
      int4 pk4;
      pk4.x = *(int*)&p0; pk4.y = *(int*)&p1;
      pk4.z = *(int*)&p2; pk4.w = *(int*)&p3;
      *(int4*)((__half*)outv + (size_t)wid * dofull + c) = pk4;
    } else {
      float* op = (float*)outv + (size_t)wid * dofull + c;
      ((float4*)op)[0] = make_float4(o[0], o[1], o[2], o[3]);
      ((float4*)op)[1] = make_float4(o[4], o[5], o[6], o[7]);
    }
  }
}

// ---------------------------------------------------------------------------
extern "C" void kernel_launch(void* const* d_in, const int* in_sizes, int n_in,
                              void* d_out, int out_size, void* d_ws, size_t ws_size,
                              hipStream_t stream) {
  const float* x   = (const float*)d_in[0];
  const int*   ei  = (const int*)d_in[1];
  const float* Wn0 = (const float*)d_in[2];
  const float* cn0 = (const float*)d_in[3];
  const float* Wr0 = (const float*)d_in[4];
  const float* cr0 = (const float*)d_in[5];
  const float* Wn1 = (const float*)d_in[6];
  const float* cn1 = (const float*)d_in[7];
  const float* Wr1 = (const float*)d_in[8];
  const float* cr1 = (const float*)d_in[9];
  const float* Wn2 = (const float*)d_in[10];
  const float* cn2 = (const float*)d_in[11];
  const float* Wr2 = (const float*)d_in[12];
  const float* cr2 = (const float*)d_in[13];
  const float* g0  = (const float*)d_in[14];
  const float* b0  = (const float*)d_in[15];
  const float* m0  = (const float*)d_in[16];
  const float* v0  = (const float*)d_in[17];
  const float* g1  = (const float*)d_in[18];
  const float* b1  = (const float*)d_in[19];
  const float* m1  = (const float*)d_in[20];
  const float* v1  = (const float*)d_in[21];

  const int* src = ei;
  const int* dst = ei + E_EDGES;

  char* p = (char*)d_ws;
  auto alloc = [&](size_t bytes) {
    char* r = p;
    p += (bytes + 255) & ~(size_t)255;
    return r;
  };
  __half*         P0      = (__half*)        alloc((size_t)N_NODES * 128 * 2);
  __half*         P1      = (__half*)        alloc((size_t)N_NODES * 128 * 2);
  __half*         A16     = (__half*)        alloc((size_t)N_NODES * 128 * 2);
  unsigned*       staging = (unsigned*)      alloc((size_t)NSB * NSUBL * SUBCAP * 4); // 8 MB
  int*            deg     = (int*)           alloc((size_t)N_NODES * 4);
  float*          denom   = (float*)         alloc((size_t)N_NODES * 4);
  int*            rowptr  = (int*)           alloc((size_t)(N_NODES + 1) * 4);
  int*            gcur    = (int*)           alloc((size_t)N_NODES * 4);
  int*            sbsum   = (int*)           alloc((size_t)NSB * 4);
  int*            sbbase  = (int*)           alloc((size_t)NSB * 4);
  int*            gc      = (int*)           alloc((size_t)(NSB * NSUBL * BSTR + 16) * 4);
  unsigned short* csrs16  = (unsigned short*)alloc((size_t)E_EDGES * 2);
  unsigned*       csrp    = (unsigned*)      alloc((size_t)E_EDGES * 4);
  __half*         WtN0    = (__half*)        alloc(128 * 128 * 2);
  __half*         WtR0    = (__half*)        alloc(128 * 128 * 2);
  __half*         WtN1    = (__half*)        alloc(128 * 128 * 2);
  __half*         WtR1    = (__half*)        alloc(128 * 128 * 2);
  __half*         WtN2    = (__half*)        alloc(64 * 128 * 2);
  __half*         WtR2    = (__half*)        alloc(64 * 128 * 2);
  float*          bias0   = (float*)         alloc(128 * 4);
  float*          bias1   = (float*)         alloc(128 * 4);
  float*          bias2   = (float*)         alloc(64 * 4);

  // overflow list aliases csrp (only written later by edge_weights; overflow
  // consumers all run before edge_weights)
  unsigned* ostage = (unsigned*)csrp;
  int*      ocnt   = gc + NSB * NSUBL * BSTR;   // covered by gc memset

  hipMemsetAsync(gc, 0, (size_t)(NSB * NSUBL * BSTR + 16) * 4, stream);

  const int node_grid = (N_NODES * 64 + 255) / 256;

  xn_norm<<<node_grid, 256, 0, stream>>>(x, P0, N_NODES);
  prep_weights<<<320, 256, 0, stream>>>(Wn0, Wr0, Wn1, Wr1, Wn2, Wr2,
                                        cn0, cr0, cn1, cr1, cn2, cr2,
                                        WtN0, WtR0, WtN1, WtR1, WtN2, WtR2,
                                        bias0, bias1, bias2);
  scatter_sb<<<SCGRID, 256, 0, stream>>>(src, dst, gc, staging, ocnt, ostage, E_EDGES);
  hist_sb<<<NSB, 256, 0, stream>>>(staging, gc, deg, sbsum, N_NODES);
  overflow_deg<<<64, 256, 0, stream>>>(ostage, ocnt, deg, sbsum);
  scan_sb<<<1, 128, 0, stream>>>(sbsum, sbbase, rowptr, N_NODES);
  rowptr_sb<<<NSB, 256, 0, stream>>>(deg, sbbase, rowptr, N_NODES);
  place_sb<<<NSB, 256, 0, stream>>>(staging, gc, rowptr, csrs16, gcur, N_NODES);
  overflow_place<<<64, 256, 0, stream>>>(ostage, ocnt, gcur, csrs16);
  edge_weights<<<node_grid, 256, 0, stream>>>(P0, rowptr, csrs16, csrp, denom, N_NODES);

  const int gemm_grid = (N_NODES + 63) / 64;

  // layer 0
  gemm_dual_mfma<128, float><<<gemm_grid, 256, 0, stream>>>(
      x, WtN0, WtR0, bias0, P0, P1, N_NODES);
  for (int pass = 0; pass < 4; ++pass)
    agg_pass<true, true><<<node_grid, 256, 0, stream>>>(
        P0 + (size_t)pass * N_NODES * 32, P1, rowptr, csrp, denom,
        g0, b0, m0, v0, A16, 128, pass * 32, N_NODES);

  // layer 1
  gemm_dual_mfma<128, __half><<<gemm_grid, 256, 0, stream>>>(
      A16, WtN1, WtR1, bias1, P0, P1, N_NODES);
  for (int pass = 0; pass < 4; ++pass)
    agg_pass<true, true><<<node_grid, 256, 0, stream>>>(
        P0 + (size_t)pass * N_NODES * 32, P1, rowptr, csrp, denom,
        g1, b1, m1, v1, A16, 128, pass * 32, N_NODES);

  // layer 2
  gemm_dual_mfma<64, __half><<<gemm_grid, 256, 0, stream>>>(
      A16, WtN2, WtR2, bias2, P0, P1, N_NODES);
  for (int pass = 0; pass < 2; ++pass)
    agg_pass<false, false><<<node_grid, 256, 0, stream>>>(
        P0 + (size_t)pass * N_NODES * 32, P1, rowptr, csrp, denom,
        nullptr, nullptr, nullptr, nullptr, d_out, 64, pass * 32, N_NODES);
}

// Round 17
// 471.487 us; speedup vs baseline: 1.1533x; 1.1152x over previous
//
#include <hip/hip_runtime.h>
#include <hip/hip_fp16.h>
#include <hip/hip_fp8.h>
#include <math.h>
#include <type_traits>

#define N_NODES 50000
#define E_EDGES 1600000
#define TAU     0.5f
#define BN_EPS  1e-5f
#define SBSH    9                        // 512 dst nodes per super-bucket
#define NSB     ((N_NODES + 511) >> 9)   // 98 super-buckets
#define NSUBL   8                        // staging sub-lists (spread cursor LINES)
#define SUBCAP  2560                     // entries per sub-list (mean 2048 + >10 sigma)
#define BINCAP  48                       // LDS bin capacity (mean 10.4, +11 sigma)
#define EPB     1024                     // edges per scatter block
#define SCGRID  ((E_EDGES + EPB - 1) / EPB)
#define BSTR    16                       // cursor stride in ints (64B/line)

typedef _Float16 f16x8 __attribute__((ext_vector_type(8)));
typedef float    f32x4 __attribute__((ext_vector_type(4)));

__device__ __forceinline__ float dot8h(int4 a, int4 b) {
  const __half2* ah = (const __half2*)&a;
  const __half2* bh = (const __half2*)&b;
  float acc = 0.0f;
  #pragma unroll
  for (int q = 0; q < 4; ++q) {
    float2 fa = __half22float2(ah[q]);
    float2 fb = __half22float2(bh[q]);
    acc = fmaf(fa.x, fb.x, acc);
    acc = fmaf(fa.y, fb.y, acc);
  }
  return acc;
}

// ---------------------------------------------------------------------------
// 1) normalized fp16 features
__global__ __launch_bounds__(256) void xn_norm(
    const float* __restrict__ x, __half* __restrict__ xn, int n) {
  int wid  = (int)((blockIdx.x * blockDim.x + threadIdx.x) >> 6);
  int lane = threadIdx.x & 63;
  if (wid >= n) return;
  float2 v = ((const float2*)(x + (size_t)wid * 128))[lane];
  float s = v.x * v.x + v.y * v.y;
  #pragma unroll
  for (int off = 32; off; off >>= 1) s += __shfl_xor(s, off);
  float inv = 1.0f / (sqrtf(s) + 1e-12f);
  ((__half2*)(xn + (size_t)wid * 128))[lane] =
      __floats2half2_rn(v.x * inv, v.y * inv);
}

// ---------------------------------------------------------------------------
// 2a) LDS-binned scatter (unchanged)
__global__ __launch_bounds__(256) void scatter_sb(
    const int* __restrict__ src, const int* __restrict__ dst,
    int* __restrict__ gc, unsigned* __restrict__ staging,
    int* __restrict__ ocnt, unsigned* __restrict__ ostage, int e) {
  __shared__ unsigned bins[NSB][BINCAP];
  __shared__ int bcount[NSB];
  const int tid  = threadIdx.x;
  const int wv   = tid >> 6;
  const int lane = tid & 63;
  const int sl   = blockIdx.x & (NSUBL - 1);
  for (int i = tid; i < NSB; i += 256) bcount[i] = 0;
  __syncthreads();

  int base = blockIdx.x * EPB;
  int bend = min(base + EPB, e);
  for (int i = base + tid; i < bend; i += 256) {
    int d = dst[i], s = src[i];
    int sb = d >> SBSH;
    int pos = atomicAdd(&bcount[sb], 1);
    if (pos < BINCAP) {
      bins[sb][pos] = (unsigned)s | ((unsigned)(d & 511) << 16);
    } else {
      int op = atomicAdd(ocnt, 1);
      ostage[op] = (unsigned)s | ((unsigned)d << 16);   // full dst
    }
  }
  __syncthreads();

  for (int sb = wv; sb < NSB; sb += 4) {
    int cnt = min(bcount[sb], BINCAP);
    if (cnt > 0) {
      int cell = sb * NSUBL + sl;
      int gbase = 0;
      if (lane == 0) gbase = atomicAdd(&gc[cell * BSTR], cnt);
      gbase = __shfl(gbase, 0);
      if (gbase + cnt <= SUBCAP) {
        if (lane < cnt)
          staging[(size_t)cell * SUBCAP + gbase + lane] = bins[sb][lane];
      } else if (lane < cnt) {
        unsigned u = bins[sb][lane];
        int op = atomicAdd(ocnt, 1);
        ostage[op] = (u & 0xFFFFu) | ((unsigned)((sb << SBSH) | (u >> 16)) << 16);
      }
    }
  }
}

// ---------------------------------------------------------------------------
// 2b) per-SB LDS histogram over the 8 sub-lists -> deg + SB total
__global__ __launch_bounds__(256) void hist_sb(
    const unsigned* __restrict__ staging, const int* __restrict__ gc,
    int* __restrict__ deg, int* __restrict__ sbsum, int n) {
  __shared__ int h[512];
  __shared__ int wt[4];
  int sb = blockIdx.x;
  for (int i = threadIdx.x; i < 512; i += 256) h[i] = 0;
  __syncthreads();
  for (int s = 0; s < NSUBL; ++s) {
    int cell = sb * NSUBL + s;
    int m = min(gc[cell * BSTR], SUBCAP);
    for (int i = threadIdx.x; i < m; i += 256)
      atomicAdd(&h[(staging[(size_t)cell * SUBCAP + i] >> 16) & 511], 1);
  }
  __syncthreads();
  int d0 = sb << SBSH;
  for (int i = threadIdx.x; i < 512; i += 256)
    if (d0 + i < n) deg[d0 + i] = h[i];
  int t = h[threadIdx.x] + h[threadIdx.x + 256];
  #pragma unroll
  for (int off = 32; off; off >>= 1) t += __shfl_xor(t, off);
  if ((threadIdx.x & 63) == 0) wt[threadIdx.x >> 6] = t;
  __syncthreads();
  if (threadIdx.x == 0) sbsum[sb] = wt[0] + wt[1] + wt[2] + wt[3];
}

// ---------------------------------------------------------------------------
// 2b') overflow patch (no-op when ocnt==0)
__global__ __launch_bounds__(256) void overflow_deg(
    const unsigned* __restrict__ ostage, const int* __restrict__ ocnt,
    int* __restrict__ deg, int* __restrict__ sbsum) {
  int m = *ocnt;
  for (int i = blockIdx.x * blockDim.x + threadIdx.x; i < m;
       i += gridDim.x * blockDim.x) {
    int d = (int)(ostage[i] >> 16);
    atomicAdd(&deg[d], 1);
    atomicAdd(&sbsum[d >> SBSH], 1);
  }
}

// ---------------------------------------------------------------------------
// 3a) exclusive scan over the 98 SB sums
__global__ void scan_sb(const int* __restrict__ sbsum, int* __restrict__ sbbase,
                        int* __restrict__ rowptr, int n) {
  __shared__ int part[128];
  int t = (int)threadIdx.x;
  int v = (t < NSB) ? sbsum[t] : 0;
  part[t] = v;
  __syncthreads();
  for (int off = 1; off < 128; off <<= 1) {
    int u = (t >= off) ? part[t - off] : 0;
    __syncthreads();
    part[t] += u;
    __syncthreads();
  }
  if (t < NSB) sbbase[t] = part[t] - v;
  if (t == 127) rowptr[n] = part[127];
}

// ---------------------------------------------------------------------------
// 3b) rowptr within SB: 512-element block scan (2 per thread)
__global__ __launch_bounds__(256) void rowptr_sb(
    const int* __restrict__ deg, const int* __restrict__ sbbase,
    int* __restrict__ rowptr, int n) {
  __shared__ int part[256];
  int sb = blockIdx.x;
  int d0 = sb << SBSH;
  int t = (int)threadIdx.x;
  int e0 = d0 + 2 * t;
  int v0 = (e0 < n) ? deg[e0] : 0;
  int v1 = (e0 + 1 < n) ? deg[e0 + 1] : 0;
  int s = v0 + v1;
  part[t] = s;
  __syncthreads();
  for (int off = 1; off < 256; off <<= 1) {
    int u = (t >= off) ? part[t - off] : 0;
    __syncthreads();
    part[t] += u;
    __syncthreads();
  }
  int ex = part[t] - s + sbbase[sb];
  if (e0 < n) rowptr[e0] = ex;
  if (e0 + 1 < n) rowptr[e0 + 1] = ex + v0;
}

// ---------------------------------------------------------------------------
// 2c) placement (unchanged)
__global__ __launch_bounds__(256) void place_sb(
    const unsigned* __restrict__ staging, const int* __restrict__ gc,
    const int* __restrict__ rowptr, unsigned short* __restrict__ csr16,
    int* __restrict__ gcur, int n) {
  __shared__ int cur[512];
  int sb = blockIdx.x;
  int d0 = sb << SBSH;
  for (int i = threadIdx.x; i < 512; i += 256)
    cur[i] = (d0 + i < n) ? rowptr[d0 + i] : 0;
  __syncthreads();
  for (int s = 0; s < NSUBL; ++s) {
    int cell = sb * NSUBL + s;
    int m = min(gc[cell * BSTR], SUBCAP);
    for (int i = threadIdx.x; i < m; i += 256) {
      unsigned u = staging[(size_t)cell * SUBCAP + i];
      int j = (u >> 16) & 511;
      int pos = atomicAdd(&cur[j], 1);
      csr16[pos] = (unsigned short)(u & 0xFFFFu);
    }
  }
  __syncthreads();
  for (int i = threadIdx.x; i < 512; i += 256)
    if (d0 + i < n) gcur[d0 + i] = cur[i];
}

// ---------------------------------------------------------------------------
// 2c') overflow placement (no-op when ocnt==0)
__global__ __launch_bounds__(256) void overflow_place(
    const unsigned* __restrict__ ostage, const int* __restrict__ ocnt,
    int* __restrict__ gcur, unsigned short* __restrict__ csr16) {
  int m = *ocnt;
  for (int i = blockIdx.x * blockDim.x + threadIdx.x; i < m;
       i += gridDim.x * blockDim.x) {
    unsigned u = ostage[i];
    int d = (int)(u >> 16);
    int pos = atomicAdd(&gcur[d], 1);
    csr16[pos] = (unsigned short)(u & 0xFFFFu);
  }
}

// ---------------------------------------------------------------------------
// 4) edge weights, dst-ordered (unchanged)
__global__ __launch_bounds__(256) void edge_weights(
    const __half* __restrict__ xn, const int* __restrict__ rowptr,
    const unsigned short* __restrict__ csr_src16,
    unsigned* __restrict__ csrp, float* __restrict__ denom, int n) {
  int wid  = (int)((blockIdx.x * blockDim.x + threadIdx.x) >> 6);
  int lane = threadIdx.x & 63;
  if (wid >= n) return;
  int grp = lane >> 3;       // edge slot 0..7
  int sub = lane & 7;        // 16-dim slice
  int beg = rowptr[wid], end = rowptr[wid + 1];
  const int4* xdp = (const int4*)(xn + (size_t)wid * 128);
  int4 xd0 = xdp[sub], xd1 = xdp[sub + 8];
  float wsum = 0.0f;

  for (int base = beg; base < end; base += 64) {
    int m = min(64, end - base);
    int sv = (lane < m) ? (int)csr_src16[base + lane] : 0;
    int iters = (m + 7) >> 3;
    #pragma unroll 2
    for (int q = 0; q < iters; ++q) {
      int ei = q * 8 + grp;
      int s = __shfl(sv, ei);
      const int4* xsp = (const int4*)(xn + (size_t)s * 128);
      int4 xs0 = xsp[sub], xs1 = xsp[sub + 8];
      float dp = dot8h(xs0, xd0) + dot8h(xs1, xd1);
      dp += __shfl_xor(dp, 1);
      dp += __shfl_xor(dp, 2);
      dp += __shfl_xor(dp, 4);
      bool valid = ei < m;
      float w = valid ? __expf(dp * (1.0f / TAU)) : 0.0f;
      wsum += w;
      if (valid && sub == 0) {
        unsigned w16 = (unsigned)__half_as_ushort(__float2half_rn(w));
        csrp[base + ei] = (unsigned)s | (w16 << 16);
      }
    }
  }
  wsum += __shfl_xor(wsum, 8);
  wsum += __shfl_xor(wsum, 16);
  wsum += __shfl_xor(wsum, 32);
  if (lane == 0) denom[wid] = wsum;
}

// ---------------------------------------------------------------------------
// 5a) weight prepack in MFMA fragment order (unchanged from R16)
__global__ __launch_bounds__(256) void prep_weights(
    const float* __restrict__ Wn0, const float* __restrict__ Wr0,
    const float* __restrict__ Wn1, const float* __restrict__ Wr1,
    const float* __restrict__ Wn2, const float* __restrict__ Wr2,
    const float* __restrict__ cn0, const float* __restrict__ cr0,
    const float* __restrict__ cn1, const float* __restrict__ cr1,
    const float* __restrict__ cn2, const float* __restrict__ cr2,
    __half* __restrict__ WtN0, __half* __restrict__ WtR0,
    __half* __restrict__ WtN1, __half* __restrict__ WtR1,
    __half* __restrict__ WtN2, __half* __restrict__ WtR2,
    float* __restrict__ bias0, float* __restrict__ bias1,
    float* __restrict__ bias2) {
  int i = blockIdx.x * blockDim.x + threadIdx.x;
  const float* Ws[6] = {Wn0, Wr0, Wn1, Wr1, Wn2, Wr2};
  __half*     Wts[6] = {WtN0, WtR0, WtN1, WtR1, WtN2, WtR2};
  int seg = -1, off = 0;
  if (i < 65536)        { seg = i >> 14;               off = i & 16383; }
  else if (i < 81920)   { int j = i - 65536; seg = 4 + (j >> 13); off = j & 8191; }
  if (seg >= 0) {
    int DO = (seg < 4) ? 128 : 64;
    int c = off >> 7, k = off & 127;
    int t = c >> 4, kc = k >> 5, kgrp = (k >> 3) & 3, j = k & 7;
    int lane = (c & 15) | (kgrp << 4);
    int idx = (((t * 4 + kc) * 64 + lane) << 3) + j;
    Wts[seg][idx] = __float2half_rn(Ws[seg][(size_t)k * DO + c]);
  }
  if (i < 128) { bias0[i] = cn0[i] + cr0[i]; bias1[i] = cn1[i] + cr1[i]; }
  if (i < 64)  { bias2[i] = cn2[i] + cr2[i]; }
}

// ---------------------------------------------------------------------------
// 5b) dual MFMA GEMM. YMODE=1: Y as fp8 e4m3 in 64-ch planes (64B/row = one
// cache line -> agg gathers serve 2x channels per line). YMODE=0: fp16 32-ch
// planes (final layer, precision).
template <int DO, typename TIN, int YMODE>
__global__ __launch_bounds__(256) void gemm_dual_mfma(
    const TIN* __restrict__ H, const __half* __restrict__ WfN,
    const __half* __restrict__ WfR, const float* __restrict__ bias,
    void* __restrict__ Yv, __half* __restrict__ Z, int n) {
  constexpr int NT = DO / 16;
  const int lane  = threadIdx.x & 63;
  const int w     = threadIdx.x >> 6;
  const int row0  = blockIdx.x * 64 + w * 16;
  const int col16 = lane & 15;
  const int kgrp  = (lane >> 4) * 8;
  const size_t arow = (size_t)min(row0 + col16, n - 1);

  f32x4 acc[2][NT];
  #pragma unroll
  for (int m = 0; m < 2; ++m)
    #pragma unroll
    for (int t = 0; t < NT; ++t) acc[m][t] = (f32x4){0.f, 0.f, 0.f, 0.f};

  #pragma unroll
  for (int kc = 0; kc < 4; ++kc) {
    f16x8 a;
    if constexpr (std::is_same<TIN, float>::value) {
      const float* hp = H + arow * 128 + kc * 32 + kgrp;
      float4 f0 = *(const float4*)hp;
      float4 f1 = *(const float4*)(hp + 4);
      a[0] = (_Float16)f0.x; a[1] = (_Float16)f0.y;
      a[2] = (_Float16)f0.z; a[3] = (_Float16)f0.w;
      a[4] = (_Float16)f1.x; a[5] = (_Float16)f1.y;
      a[6] = (_Float16)f1.z; a[7] = (_Float16)f1.w;
    } else {
      a = *(const f16x8*)(H + arow * 128 + kc * 32 + kgrp);
    }
    const f16x8* bN = (const f16x8*)(WfN + ((size_t)(kc * 64 + lane) << 3));
    const f16x8* bR = (const f16x8*)(WfR + ((size_t)(kc * 64 + lane) << 3));
    #pragma unroll
    for (int t = 0; t < NT; ++t) {
      f16x8 b = bN[t * 256];
      acc[0][t] = __builtin_amdgcn_mfma_f32_16x16x32_f16(a, b, acc[0][t], 0, 0, 0);
    }
    #pragma unroll
    for (int t = 0; t < NT; ++t) {
      f16x8 b = bR[t * 256];
      acc[1][t] = __builtin_amdgcn_mfma_f32_16x16x32_f16(a, b, acc[1][t], 0, 0, 0);
    }
  }

  const int rbase = (lane >> 4) * 4;
  #pragma unroll
  for (int t = 0; t < NT; ++t) {
    int col = t * 16 + col16;
    float bz = bias[col];
    #pragma unroll
    for (int j = 0; j < 4; ++j) {
      int row = row0 + rbase + j;
      if (row < n) {
        if constexpr (YMODE == 1) {
          int pidx = col >> 6, incol = col & 63;
          __hip_fp8_e4m3 q(acc[0][t][j]);
          ((unsigned char*)Yv)[((size_t)pidx * n + row) * 64 + incol] = q.__x;
        } else {
          int pidx = col >> 5, incol = col & 31;
          ((__half*)Yv)[((size_t)pidx * n + row) * 32 + incol] =
              __float2half_rn(acc[0][t][j]);
        }
        Z[(size_t)row * DO + col] = __float2half_rn(acc[1][t][j] + bz);
      }
    }
  }
}

// ---------------------------------------------------------------------------
// 6) aggregation pass over ONE plane. FP8Y: 64-ch fp8 plane (64B/row, same
// 3.2MB L2 working set as 32-ch fp16 but half the passes). 16 edges in
// flight per wave (4 lanes/edge, int4 each).
template <bool DO_BN, bool HALF_OUT, bool FP8Y>
__global__ __launch_bounds__(256) void agg_pass(
    const void* __restrict__ Ypv, const __half* __restrict__ Zb,
    const int* __restrict__ rowptr, const unsigned* __restrict__ csrp,
    const float* __restrict__ denom,
    const float* __restrict__ g, const float* __restrict__ bb,
    const float* __restrict__ mm, const float* __restrict__ vv,
    void* __restrict__ outv, int dofull, int choff, int n) {
  constexpr int CH = FP8Y ? 16 : 8;    // channels per lane
  int wid  = (int)((blockIdx.x * blockDim.x + threadIdx.x) >> 6);
  int lane = threadIdx.x & 63;
  if (wid >= n) return;
  int grp = lane >> 2;     // edge slot 0..15
  int sub = lane & 3;      // channel group 0..3
  int beg = rowptr[wid], end = rowptr[wid + 1];
  float inv = 1.0f / (denom[wid] + 1e-16f);

  float a[CH];
  #pragma unroll
  for (int k = 0; k < CH; ++k) a[k] = 0.0f;

  for (int base = beg; base < end; base += 64) {
    int m = min(64, end - base);
    unsigned pk = (lane < m) ? csrp[base + lane] : 0u;   // w=0 when inactive
    int iters = (m + 15) >> 4;
    #pragma unroll 4
    for (int q = 0; q < iters; ++q) {
      unsigned u = __shfl(pk, q * 16 + grp);
      int   s = (int)(u & 0xFFFFu);
      float w = __half2float(__ushort_as_half((unsigned short)(u >> 16)));
      if constexpr (FP8Y) {
        int4 raw = ((const int4*)((const unsigned char*)Ypv + (size_t)s * 64))[sub];
        unsigned ww[4] = {(unsigned)raw.x, (unsigned)raw.y,
                          (unsigned)raw.z, (unsigned)raw.w};
        #pragma unroll
        for (int wi = 0; wi < 4; ++wi) {
          #pragma unroll
          for (int b = 0; b < 4; ++b) {
            __hip_fp8_e4m3 q8;
            q8.__x = (__hip_fp8_storage_t)((ww[wi] >> (8 * b)) & 0xFF);
            a[wi * 4 + b] = fmaf(w, (float)q8, a[wi * 4 + b]);
          }
        }
      } else {
        int4 raw = ((const int4*)((const __half*)Ypv + (size_t)s * 32))[sub];
        const __half2* hh = (const __half2*)&raw;
        #pragma unroll
        for (int k = 0; k < 4; ++k) {
          float2 f = __half22float2(hh[k]);
          a[2 * k]     = fmaf(w, f.x, a[2 * k]);
          a[2 * k + 1] = fmaf(w, f.y, a[2 * k + 1]);
        }
      }
    }
  }
  #pragma unroll
  for (int off = 32; off >= 4; off >>= 1) {
    #pragma unroll
    for (int k = 0; k < CH; ++k) a[k] += __shfl_xor(a[k], off);
  }

  if (lane < 4) {
    int c = choff + sub * CH;
    float o[CH];
    const int4* zp = (const int4*)(Zb + (size_t)wid * dofull + c);
    #pragma unroll
    for (int v = 0; v < CH / 8; ++v) {
      int4 zr = zp[v];
      const __half2* zh = (const __half2*)&zr;
      #pragma unroll
      for (int k = 0; k < 4; ++k) {
        float2 z = __half22float2(zh[k]);
        o[v * 8 + 2 * k]     = fmaf(a[v * 8 + 2 * k], inv, z.x);
        o[v * 8 + 2 * k + 1] = fmaf(a[v * 8 + 2 * k + 1], inv, z.y);
      }
    }
    if constexpr (DO_BN) {
      #pragma unroll
      for (int k = 0; k < CH; ++k) {
        float sc = g[c + k] * rsqrtf(vv[c + k] + BN_EPS);
        o[k] = fmaxf(fmaf(o[k] - mm[c + k], sc, bb[c + k]), 0.0f);
      }
    }
    if constexpr (HALF_OUT) {
      #pragma unroll
      for (int v = 0; v < CH / 8; ++v) {
        __half2 p0 = __floats2half2_rn(o[v * 8 + 0], o[v * 8 + 1]);
        __half2 p1 = __floats2half2_rn(o[v * 8 + 2], o[v * 8 + 3]);
        __half2 p2 = __floats2half2_rn(o[v * 8 + 4], o[v * 8 + 5]);
        __half2 p3 = __floats2half2_rn(o[v * 8 + 6], o[v * 8 + 7]);
        int4 pk4;
        pk4.x = *(int*)&p0; pk4.y = *(int*)&p1;
        pk4.z = *(int*)&p2; pk4.w = *(int*)&p3;
        ((int4*)((__half*)outv + (size_t)wid * dofull + c))[v] = pk4;
      }
    } else {
      float* op = (float*)outv + (size_t)wid * dofull + c;
      #pragma unroll
      for (int v = 0; v < CH / 4; ++v)
        ((float4*)op)[v] = make_float4(o[v * 4], o[v * 4 + 1],
                                       o[v * 4 + 2], o[v * 4 + 3]);
    }
  }
}

// ---------------------------------------------------------------------------
extern "C" void kernel_launch(void* const* d_in, const int* in_sizes, int n_in,
                              void* d_out, int out_size, void* d_ws, size_t ws_size,
                              hipStream_t stream) {
  const float* x   = (const float*)d_in[0];
  const int*   ei  = (const int*)d_in[1];
  const float* Wn0 = (const float*)d_in[2];
  const float* cn0 = (const float*)d_in[3];
  const float* Wr0 = (const float*)d_in[4];
  const float* cr0 = (const float*)d_in[5];
  const float* Wn1 = (const float*)d_in[6];
  const float* cn1 = (const float*)d_in[7];
  const float* Wr1 = (const float*)d_in[8];
  const float* cr1 = (const float*)d_in[9];
  const float* Wn2 = (const float*)d_in[10];
  const float* cn2 = (const float*)d_in[11];
  const float* Wr2 = (const float*)d_in[12];
  const float* cr2 = (const float*)d_in[13];
  const float* g0  = (const float*)d_in[14];
  const float* b0  = (const float*)d_in[15];
  const float* m0  = (const float*)d_in[16];
  const float* v0  = (const float*)d_in[17];
  const float* g1  = (const float*)d_in[18];
  const float* b1  = (const float*)d_in[19];
  const float* m1  = (const float*)d_in[20];
  const float* v1  = (const float*)d_in[21];

  const int* src = ei;
  const int* dst = ei + E_EDGES;

  char* p = (char*)d_ws;
  auto alloc = [&](size_t bytes) {
    char* r = p;
    p += (bytes + 255) & ~(size_t)255;
    return r;
  };
  __half*         P0      = (__half*)        alloc((size_t)N_NODES * 128 * 2);
  __half*         P1      = (__half*)        alloc((size_t)N_NODES * 128 * 2);
  __half*         A16     = (__half*)        alloc((size_t)N_NODES * 128 * 2);
  unsigned*       staging = (unsigned*)      alloc((size_t)NSB * NSUBL * SUBCAP * 4); // 8 MB
  int*            deg     = (int*)           alloc((size_t)N_NODES * 4);
  float*          denom   = (float*)         alloc((size_t)N_NODES * 4);
  int*            rowptr  = (int*)           alloc((size_t)(N_NODES + 1) * 4);
  int*            gcur    = (int*)           alloc((size_t)N_NODES * 4);
  int*            sbsum   = (int*)           alloc((size_t)NSB * 4);
  int*            sbbase  = (int*)           alloc((size_t)NSB * 4);
  int*            gc      = (int*)           alloc((size_t)(NSB * NSUBL * BSTR + 16) * 4);
  unsigned short* csrs16  = (unsigned short*)alloc((size_t)E_EDGES * 2);
  unsigned*       csrp    = (unsigned*)      alloc((size_t)E_EDGES * 4);
  __half*         WtN0    = (__half*)        alloc(128 * 128 * 2);
  __half*         WtR0    = (__half*)        alloc(128 * 128 * 2);
  __half*         WtN1    = (__half*)        alloc(128 * 128 * 2);
  __half*         WtR1    = (__half*)        alloc(128 * 128 * 2);
  __half*         WtN2    = (__half*)        alloc(64 * 128 * 2);
  __half*         WtR2    = (__half*)        alloc(64 * 128 * 2);
  float*          bias0   = (float*)         alloc(128 * 4);
  float*          bias1   = (float*)         alloc(128 * 4);
  float*          bias2   = (float*)         alloc(64 * 4);

  // fp8 Y planes (hidden layers) alias P0: xn lives there but is dead after
  // edge_weights, which runs before the first gemm. 6.4 MB < P0's 12.8 MB.
  unsigned char* Y8 = (unsigned char*)P0;

  // overflow list aliases csrp (only written later by edge_weights)
  unsigned* ostage = (unsigned*)csrp;
  int*      ocnt   = gc + NSB * NSUBL * BSTR;   // covered by gc memset

  hipMemsetAsync(gc, 0, (size_t)(NSB * NSUBL * BSTR + 16) * 4, stream);

  const int node_grid = (N_NODES * 64 + 255) / 256;

  xn_norm<<<node_grid, 256, 0, stream>>>(x, P0, N_NODES);
  prep_weights<<<320, 256, 0, stream>>>(Wn0, Wr0, Wn1, Wr1, Wn2, Wr2,
                                        cn0, cr0, cn1, cr1, cn2, cr2,
                                        WtN0, WtR0, WtN1, WtR1, WtN2, WtR2,
                                        bias0, bias1, bias2);
  scatter_sb<<<SCGRID, 256, 0, stream>>>(src, dst, gc, staging, ocnt, ostage, E_EDGES);
  hist_sb<<<NSB, 256, 0, stream>>>(staging, gc, deg, sbsum, N_NODES);
  overflow_deg<<<64, 256, 0, stream>>>(ostage, ocnt, deg, sbsum);
  scan_sb<<<1, 128, 0, stream>>>(sbsum, sbbase, rowptr, N_NODES);
  rowptr_sb<<<NSB, 256, 0, stream>>>(deg, sbbase, rowptr, N_NODES);
  place_sb<<<NSB, 256, 0, stream>>>(staging, gc, rowptr, csrs16, gcur, N_NODES);
  overflow_place<<<64, 256, 0, stream>>>(ostage, ocnt, gcur, csrs16);
  edge_weights<<<node_grid, 256, 0, stream>>>(P0, rowptr, csrs16, csrp, denom, N_NODES);

  const int gemm_grid = (N_NODES + 63) / 64;

  // layer 0: H = x (f32), Y -> fp8 64-ch planes in Y8, Z -> P1, out -> A16
  gemm_dual_mfma<128, float, 1><<<gemm_grid, 256, 0, stream>>>(
      x, WtN0, WtR0, bias0, Y8, P1, N_NODES);
  for (int pass = 0; pass < 2; ++pass)
    agg_pass<true, true, true><<<node_grid, 256, 0, stream>>>(
        Y8 + (size_t)pass * N_NODES * 64, P1, rowptr, csrp, denom,
        g0, b0, m0, v0, A16, 128, pass * 64, N_NODES);

  // layer 1: H = A16 (fp16)
  gemm_dual_mfma<128, __half, 1><<<gemm_grid, 256, 0, stream>>>(
      A16, WtN1, WtR1, bias1, Y8, P1, N_NODES);
  for (int pass = 0; pass < 2; ++pass)
    agg_pass<true, true, true><<<node_grid, 256, 0, stream>>>(
        Y8 + (size_t)pass * N_NODES * 64, P1, rowptr, csrp, denom,
        g1, b1, m1, v1, A16, 128, pass * 64, N_NODES);

  // layer 2 (64-wide, fp16 planes for output precision, straight to d_out)
  gemm_dual_mfma<64, __half, 0><<<gemm_grid, 256, 0, stream>>>(
      A16, WtN2, WtR2, bias2, P0, P1, N_NODES);
  for (int pass = 0; pass < 2; ++pass)
    agg_pass<false, false, false><<<node_grid, 256, 0, stream>>>(
        P0 + (size_t)pass * N_NODES * 32, P1, rowptr, csrp, denom,
        nullptr, nullptr, nullptr, nullptr, d_out, 64, pass * 32, N_NODES);
}

// Round 18
// 467.207 us; speedup vs baseline: 1.1639x; 1.0092x over previous
//
#include <hip/hip_runtime.h>
#include <hip/hip_fp16.h>
#include <hip/hip_fp8.h>
#include <math.h>
#include <type_traits>

#define N_NODES 50000
#define E_EDGES 1600000
#define TAU     0.5f
#define BN_EPS  1e-5f
#define SBSH    9                        // 512 dst nodes per super-bucket
#define NSB     ((N_NODES + 511) >> 9)   // 98 super-buckets
#define NSUBL   8                        // staging sub-lists (spread cursor LINES)
#define SUBCAP  2560                     // entries per sub-list (mean 2048 + >10 sigma)
#define BINCAP  48                       // LDS bin capacity (mean 10.4, +11 sigma)
#define EPB     1024                     // edges per scatter block
#define SCGRID  ((E_EDGES + EPB - 1) / EPB)
#define BSTR    16                       // cursor stride in ints (64B/line)

typedef _Float16 f16x8 __attribute__((ext_vector_type(8)));
typedef float    f32x4 __attribute__((ext_vector_type(4)));
typedef float    f32x2 __attribute__((ext_vector_type(2)));

__device__ __forceinline__ float dot8h(int4 a, int4 b) {
  const __half2* ah = (const __half2*)&a;
  const __half2* bh = (const __half2*)&b;
  float acc = 0.0f;
  #pragma unroll
  for (int q = 0; q < 4; ++q) {
    float2 fa = __half22float2(ah[q]);
    float2 fb = __half22float2(bh[q]);
    acc = fmaf(fa.x, fb.x, acc);
    acc = fmaf(fa.y, fb.y, acc);
  }
  return acc;
}

// ---------------------------------------------------------------------------
// 1) normalized fp16 features
__global__ __launch_bounds__(256) void xn_norm(
    const float* __restrict__ x, __half* __restrict__ xn, int n) {
  int wid  = (int)((blockIdx.x * blockDim.x + threadIdx.x) >> 6);
  int lane = threadIdx.x & 63;
  if (wid >= n) return;
  float2 v = ((const float2*)(x + (size_t)wid * 128))[lane];
  float s = v.x * v.x + v.y * v.y;
  #pragma unroll
  for (int off = 32; off; off >>= 1) s += __shfl_xor(s, off);
  float inv = 1.0f / (sqrtf(s) + 1e-12f);
  ((__half2*)(xn + (size_t)wid * 128))[lane] =
      __floats2half2_rn(v.x * inv, v.y * inv);
}

// ---------------------------------------------------------------------------
// 2a) LDS-binned scatter (unchanged)
__global__ __launch_bounds__(256) void scatter_sb(
    const int* __restrict__ src, const int* __restrict__ dst,
    int* __restrict__ gc, unsigned* __restrict__ staging,
    int* __restrict__ ocnt, unsigned* __restrict__ ostage, int e) {
  __shared__ unsigned bins[NSB][BINCAP];
  __shared__ int bcount[NSB];
  const int tid  = threadIdx.x;
  const int wv   = tid >> 6;
  const int lane = tid & 63;
  const int sl   = blockIdx.x & (NSUBL - 1);
  for (int i = tid; i < NSB; i += 256) bcount[i] = 0;
  __syncthreads();

  int base = blockIdx.x * EPB;
  int bend = min(base + EPB, e);
  for (int i = base + tid; i < bend; i += 256) {
    int d = dst[i], s = src[i];
    int sb = d >> SBSH;
    int pos = atomicAdd(&bcount[sb], 1);
    if (pos < BINCAP) {
      bins[sb][pos] = (unsigned)s | ((unsigned)(d & 511) << 16);
    } else {
      int op = atomicAdd(ocnt, 1);
      ostage[op] = (unsigned)s | ((unsigned)d << 16);   // full dst
    }
  }
  __syncthreads();

  for (int sb = wv; sb < NSB; sb += 4) {
    int cnt = min(bcount[sb], BINCAP);
    if (cnt > 0) {
      int cell = sb * NSUBL + sl;
      int gbase = 0;
      if (lane == 0) gbase = atomicAdd(&gc[cell * BSTR], cnt);
      gbase = __shfl(gbase, 0);
      if (gbase + cnt <= SUBCAP) {
        if (lane < cnt)
          staging[(size_t)cell * SUBCAP + gbase + lane] = bins[sb][lane];
      } else if (lane < cnt) {
        unsigned u = bins[sb][lane];
        int op = atomicAdd(ocnt, 1);
        ostage[op] = (u & 0xFFFFu) | ((unsigned)((sb << SBSH) | (u >> 16)) << 16);
      }
    }
  }
}

// ---------------------------------------------------------------------------
// 2b) per-SB LDS histogram over the 8 sub-lists -> deg + SB total
__global__ __launch_bounds__(256) void hist_sb(
    const unsigned* __restrict__ staging, const int* __restrict__ gc,
    int* __restrict__ deg, int* __restrict__ sbsum, int n) {
  __shared__ int h[512];
  __shared__ int wt[4];
  int sb = blockIdx.x;
  for (int i = threadIdx.x; i < 512; i += 256) h[i] = 0;
  __syncthreads();
  for (int s = 0; s < NSUBL; ++s) {
    int cell = sb * NSUBL + s;
    int m = min(gc[cell * BSTR], SUBCAP);
    for (int i = threadIdx.x; i < m; i += 256)
      atomicAdd(&h[(staging[(size_t)cell * SUBCAP + i] >> 16) & 511], 1);
  }
  __syncthreads();
  int d0 = sb << SBSH;
  for (int i = threadIdx.x; i < 512; i += 256)
    if (d0 + i < n) deg[d0 + i] = h[i];
  int t = h[threadIdx.x] + h[threadIdx.x + 256];
  #pragma unroll
  for (int off = 32; off; off >>= 1) t += __shfl_xor(t, off);
  if ((threadIdx.x & 63) == 0) wt[threadIdx.x >> 6] = t;
  __syncthreads();
  if (threadIdx.x == 0) sbsum[sb] = wt[0] + wt[1] + wt[2] + wt[3];
}

// ---------------------------------------------------------------------------
// 2b') overflow patch (no-op when ocnt==0)
__global__ __launch_bounds__(256) void overflow_deg(
    const unsigned* __restrict__ ostage, const int* __restrict__ ocnt,
    int* __restrict__ deg, int* __restrict__ sbsum) {
  int m = *ocnt;
  for (int i = blockIdx.x * blockDim.x + threadIdx.x; i < m;
       i += gridDim.x * blockDim.x) {
    int d = (int)(ostage[i] >> 16);
    atomicAdd(&deg[d], 1);
    atomicAdd(&sbsum[d >> SBSH], 1);
  }
}

// ---------------------------------------------------------------------------
// 3a) exclusive scan over the 98 SB sums
__global__ void scan_sb(const int* __restrict__ sbsum, int* __restrict__ sbbase,
                        int* __restrict__ rowptr, int n) {
  __shared__ int part[128];
  int t = (int)threadIdx.x;
  int v = (t < NSB) ? sbsum[t] : 0;
  part[t] = v;
  __syncthreads();
  for (int off = 1; off < 128; off <<= 1) {
    int u = (t >= off) ? part[t - off] : 0;
    __syncthreads();
    part[t] += u;
    __syncthreads();
  }
  if (t < NSB) sbbase[t] = part[t] - v;
  if (t == 127) rowptr[n] = part[127];
}

// ---------------------------------------------------------------------------
// 3b) rowptr within SB: 512-element block scan (2 per thread)
__global__ __launch_bounds__(256) void rowptr_sb(
    const int* __restrict__ deg, const int* __restrict__ sbbase,
    int* __restrict__ rowptr, int n) {
  __shared__ int part[256];
  int sb = blockIdx.x;
  int d0 = sb << SBSH;
  int t = (int)threadIdx.x;
  int e0 = d0 + 2 * t;
  int v0 = (e0 < n) ? deg[e0] : 0;
  int v1 = (e0 + 1 < n) ? deg[e0 + 1] : 0;
  int s = v0 + v1;
  part[t] = s;
  __syncthreads();
  for (int off = 1; off < 256; off <<= 1) {
    int u = (t >= off) ? part[t - off] : 0;
    __syncthreads();
    part[t] += u;
    __syncthreads();
  }
  int ex = part[t] - s + sbbase[sb];
  if (e0 < n) rowptr[e0] = ex;
  if (e0 + 1 < n) rowptr[e0 + 1] = ex + v0;
}

// ---------------------------------------------------------------------------
// 2c) placement (unchanged)
__global__ __launch_bounds__(256) void place_sb(
    const unsigned* __restrict__ staging, const int* __restrict__ gc,
    const int* __restrict__ rowptr, unsigned short* __restrict__ csr16,
    int* __restrict__ gcur, int n) {
  __shared__ int cur[512];
  int sb = blockIdx.x;
  int d0 = sb << SBSH;
  for (int i = threadIdx.x; i < 512; i += 256)
    cur[i] = (d0 + i < n) ? rowptr[d0 + i] : 0;
  __syncthreads();
  for (int s = 0; s < NSUBL; ++s) {
    int cell = sb * NSUBL + s;
    int m = min(gc[cell * BSTR], SUBCAP);
    for (int i = threadIdx.x; i < m; i += 256) {
      unsigned u = staging[(size_t)cell * SUBCAP + i];
      int j = (u >> 16) & 511;
      int pos = atomicAdd(&cur[j], 1);
      csr16[pos] = (unsigned short)(u & 0xFFFFu);
    }
  }
  __syncthreads();
  for (int i = threadIdx.x; i < 512; i += 256)
    if (d0 + i < n) gcur[d0 + i] = cur[i];
}

// ---------------------------------------------------------------------------
// 2c') overflow placement (no-op when ocnt==0)
__global__ __launch_bounds__(256) void overflow_place(
    const unsigned* __restrict__ ostage, const int* __restrict__ ocnt,
    int* __restrict__ gcur, unsigned short* __restrict__ csr16) {
  int m = *ocnt;
  for (int i = blockIdx.x * blockDim.x + threadIdx.x; i < m;
       i += gridDim.x * blockDim.x) {
    unsigned u = ostage[i];
    int d = (int)(u >> 16);
    int pos = atomicAdd(&gcur[d], 1);
    csr16[pos] = (unsigned short)(u & 0xFFFFu);
  }
}

// ---------------------------------------------------------------------------
// 4) edge weights, dst-ordered (unchanged)
__global__ __launch_bounds__(256) void edge_weights(
    const __half* __restrict__ xn, const int* __restrict__ rowptr,
    const unsigned short* __restrict__ csr_src16,
    unsigned* __restrict__ csrp, float* __restrict__ denom, int n) {
  int wid  = (int)((blockIdx.x * blockDim.x + threadIdx.x) >> 6);
  int lane = threadIdx.x & 63;
  if (wid >= n) return;
  int grp = lane >> 3;       // edge slot 0..7
  int sub = lane & 7;        // 16-dim slice
  int beg = rowptr[wid], end = rowptr[wid + 1];
  const int4* xdp = (const int4*)(xn + (size_t)wid * 128);
  int4 xd0 = xdp[sub], xd1 = xdp[sub + 8];
  float wsum = 0.0f;

  for (int base = beg; base < end; base += 64) {
    int m = min(64, end - base);
    int sv = (lane < m) ? (int)csr_src16[base + lane] : 0;
    int iters = (m + 7) >> 3;
    #pragma unroll 2
    for (int q = 0; q < iters; ++q) {
      int ei = q * 8 + grp;
      int s = __shfl(sv, ei);
      const int4* xsp = (const int4*)(xn + (size_t)s * 128);
      int4 xs0 = xsp[sub], xs1 = xsp[sub + 8];
      float dp = dot8h(xs0, xd0) + dot8h(xs1, xd1);
      dp += __shfl_xor(dp, 1);
      dp += __shfl_xor(dp, 2);
      dp += __shfl_xor(dp, 4);
      bool valid = ei < m;
      float w = valid ? __expf(dp * (1.0f / TAU)) : 0.0f;
      wsum += w;
      if (valid && sub == 0) {
        unsigned w16 = (unsigned)__half_as_ushort(__float2half_rn(w));
        csrp[base + ei] = (unsigned)s | (w16 << 16);
      }
    }
  }
  wsum += __shfl_xor(wsum, 8);
  wsum += __shfl_xor(wsum, 16);
  wsum += __shfl_xor(wsum, 32);
  if (lane == 0) denom[wid] = wsum;
}

// ---------------------------------------------------------------------------
// 5a) weight prepack in MFMA fragment order (unchanged)
__global__ __launch_bounds__(256) void prep_weights(
    const float* __restrict__ Wn0, const float* __restrict__ Wr0,
    const float* __restrict__ Wn1, const float* __restrict__ Wr1,
    const float* __restrict__ Wn2, const float* __restrict__ Wr2,
    const float* __restrict__ cn0, const float* __restrict__ cr0,
    const float* __restrict__ cn1, const float* __restrict__ cr1,
    const float* __restrict__ cn2, const float* __restrict__ cr2,
    __half* __restrict__ WtN0, __half* __restrict__ WtR0,
    __half* __restrict__ WtN1, __half* __restrict__ WtR1,
    __half* __restrict__ WtN2, __half* __restrict__ WtR2,
    float* __restrict__ bias0, float* __restrict__ bias1,
    float* __restrict__ bias2) {
  int i = blockIdx.x * blockDim.x + threadIdx.x;
  const float* Ws[6] = {Wn0, Wr0, Wn1, Wr1, Wn2, Wr2};
  __half*     Wts[6] = {WtN0, WtR0, WtN1, WtR1, WtN2, WtR2};
  int seg = -1, off = 0;
  if (i < 65536)        { seg = i >> 14;               off = i & 16383; }
  else if (i < 81920)   { int j = i - 65536; seg = 4 + (j >> 13); off = j & 8191; }
  if (seg >= 0) {
    int DO = (seg < 4) ? 128 : 64;
    int c = off >> 7, k = off & 127;
    int t = c >> 4, kc = k >> 5, kgrp = (k >> 3) & 3, j = k & 7;
    int lane = (c & 15) | (kgrp << 4);
    int idx = (((t * 4 + kc) * 64 + lane) << 3) + j;
    Wts[seg][idx] = __float2half_rn(Ws[seg][(size_t)k * DO + c]);
  }
  if (i < 128) { bias0[i] = cn0[i] + cr0[i]; bias1[i] = cn1[i] + cr1[i]; }
  if (i < 64)  { bias2[i] = cn2[i] + cr2[i]; }
}

// ---------------------------------------------------------------------------
// 5b) dual MFMA GEMM (unchanged from R17)
template <int DO, typename TIN, int YMODE>
__global__ __launch_bounds__(256) void gemm_dual_mfma(
    const TIN* __restrict__ H, const __half* __restrict__ WfN,
    const __half* __restrict__ WfR, const float* __restrict__ bias,
    void* __restrict__ Yv, __half* __restrict__ Z, int n) {
  constexpr int NT = DO / 16;
  const int lane  = threadIdx.x & 63;
  const int w     = threadIdx.x >> 6;
  const int row0  = blockIdx.x * 64 + w * 16;
  const int col16 = lane & 15;
  const int kgrp  = (lane >> 4) * 8;
  const size_t arow = (size_t)min(row0 + col16, n - 1);

  f32x4 acc[2][NT];
  #pragma unroll
  for (int m = 0; m < 2; ++m)
    #pragma unroll
    for (int t = 0; t < NT; ++t) acc[m][t] = (f32x4){0.f, 0.f, 0.f, 0.f};

  #pragma unroll
  for (int kc = 0; kc < 4; ++kc) {
    f16x8 a;
    if constexpr (std::is_same<TIN, float>::value) {
      const float* hp = H + arow * 128 + kc * 32 + kgrp;
      float4 f0 = *(const float4*)hp;
      float4 f1 = *(const float4*)(hp + 4);
      a[0] = (_Float16)f0.x; a[1] = (_Float16)f0.y;
      a[2] = (_Float16)f0.z; a[3] = (_Float16)f0.w;
      a[4] = (_Float16)f1.x; a[5] = (_Float16)f1.y;
      a[6] = (_Float16)f1.z; a[7] = (_Float16)f1.w;
    } else {
      a = *(const f16x8*)(H + arow * 128 + kc * 32 + kgrp);
    }
    const f16x8* bN = (const f16x8*)(WfN + ((size_t)(kc * 64 + lane) << 3));
    const f16x8* bR = (const f16x8*)(WfR + ((size_t)(kc * 64 + lane) << 3));
    #pragma unroll
    for (int t = 0; t < NT; ++t) {
      f16x8 b = bN[t * 256];
      acc[0][t] = __builtin_amdgcn_mfma_f32_16x16x32_f16(a, b, acc[0][t], 0, 0, 0);
    }
    #pragma unroll
    for (int t = 0; t < NT; ++t) {
      f16x8 b = bR[t * 256];
      acc[1][t] = __builtin_amdgcn_mfma_f32_16x16x32_f16(a, b, acc[1][t], 0, 0, 0);
    }
  }

  const int rbase = (lane >> 4) * 4;
  #pragma unroll
  for (int t = 0; t < NT; ++t) {
    int col = t * 16 + col16;
    float bz = bias[col];
    #pragma unroll
    for (int j = 0; j < 4; ++j) {
      int row = row0 + rbase + j;
      if (row < n) {
        if constexpr (YMODE == 1) {
          int pidx = col >> 6, incol = col & 63;
          __hip_fp8_e4m3 q(acc[0][t][j]);
          ((unsigned char*)Yv)[((size_t)pidx * n + row) * 64 + incol] = q.__x;
        } else {
          int pidx = col >> 5, incol = col & 31;
          ((__half*)Yv)[((size_t)pidx * n + row) * 32 + incol] =
              __float2half_rn(acc[0][t][j]);
        }
        Z[(size_t)row * DO + col] = __float2half_rn(acc[1][t][j] + bz);
      }
    }
  }
}

// ---------------------------------------------------------------------------
// 6) aggregation pass over ONE plane. FP8Y: 64-ch fp8 plane, unpacked with
// HW packed conversion v_cvt_pk_f32_fp8 (2 fp8 -> 2 f32 per instruction;
// R17's byte-wise unpack was VALU-bound at 78% VALUBusy).
template <bool DO_BN, bool HALF_OUT, bool FP8Y>
__global__ __launch_bounds__(256) void agg_pass(
    const void* __restrict__ Ypv, const __half* __restrict__ Zb,
    const int* __restrict__ rowptr, const unsigned* __restrict__ csrp,
    const float* __restrict__ denom,
    const float* __restrict__ g, const float* __restrict__ bb,
    const float* __restrict__ mm, const float* __restrict__ vv,
    void* __restrict__ outv, int dofull, int choff, int n) {
  constexpr int CH = FP8Y ? 16 : 8;    // channels per lane
  int wid  = (int)((blockIdx.x * blockDim.x + threadIdx.x) >> 6);
  int lane = threadIdx.x & 63;
  if (wid >= n) return;
  int grp = lane >> 2;     // edge slot 0..15
  int sub = lane & 3;      // channel group 0..3
  int beg = rowptr[wid], end = rowptr[wid + 1];
  float inv = 1.0f / (denom[wid] + 1e-16f);

  float a[CH];
  #pragma unroll
  for (int k = 0; k < CH; ++k) a[k] = 0.0f;

  for (int base = beg; base < end; base += 64) {
    int m = min(64, end - base);
    unsigned pk = (lane < m) ? csrp[base + lane] : 0u;   // w=0 when inactive
    int iters = (m + 15) >> 4;
    #pragma unroll 4
    for (int q = 0; q < iters; ++q) {
      unsigned u = __shfl(pk, q * 16 + grp);
      int   s = (int)(u & 0xFFFFu);
      float w = __half2float(__ushort_as_half((unsigned short)(u >> 16)));
      if constexpr (FP8Y) {
        int4 raw = ((const int4*)((const unsigned char*)Ypv + (size_t)s * 64))[sub];
        unsigned ww[4] = {(unsigned)raw.x, (unsigned)raw.y,
                          (unsigned)raw.z, (unsigned)raw.w};
        #pragma unroll
        for (int wi = 0; wi < 4; ++wi) {
          f32x2 lo = __builtin_amdgcn_cvt_pk_f32_fp8(ww[wi], false);
          f32x2 hi = __builtin_amdgcn_cvt_pk_f32_fp8(ww[wi], true);
          a[wi * 4 + 0] = fmaf(w, lo[0], a[wi * 4 + 0]);
          a[wi * 4 + 1] = fmaf(w, lo[1], a[wi * 4 + 1]);
          a[wi * 4 + 2] = fmaf(w, hi[0], a[wi * 4 + 2]);
          a[wi * 4 + 3] = fmaf(w, hi[1], a[wi * 4 + 3]);
        }
      } else {
        int4 raw = ((const int4*)((const __half*)Ypv + (size_t)s * 32))[sub];
        const __half2* hh = (const __half2*)&raw;
        #pragma unroll
        for (int k = 0; k < 4; ++k) {
          float2 f = __half22float2(hh[k]);
          a[2 * k]     = fmaf(w, f.x, a[2 * k]);
          a[2 * k + 1] = fmaf(w, f.y, a[2 * k + 1]);
        }
      }
    }
  }
  #pragma unroll
  for (int off = 32; off >= 4; off >>= 1) {
    #pragma unroll
    for (int k = 0; k < CH; ++k) a[k] += __shfl_xor(a[k], off);
  }

  if (lane < 4) {
    int c = choff + sub * CH;
    float o[CH];
    const int4* zp = (const int4*)(Zb + (size_t)wid * dofull + c);
    #pragma unroll
    for (int v = 0; v < CH / 8; ++v) {
      int4 zr = zp[v];
      const __half2* zh = (const __half2*)&zr;
      #pragma unroll
      for (int k = 0; k < 4; ++k) {
        float2 z = __half22float2(zh[k]);
        o[v * 8 + 2 * k]     = fmaf(a[v * 8 + 2 * k], inv, z.x);
        o[v * 8 + 2 * k + 1] = fmaf(a[v * 8 + 2 * k + 1], inv, z.y);
      }
    }
    if constexpr (DO_BN) {
      #pragma unroll
      for (int k = 0; k < CH; ++k) {
        float sc = g[c + k] * rsqrtf(vv[c + k] + BN_EPS);
        o[k] = fmaxf(fmaf(o[k] - mm[c + k], sc, bb[c + k]), 0.0f);
      }
    }
    if constexpr (HALF_OUT) {
      #pragma unroll
      for (int v = 0; v < CH / 8; ++v) {
        __half2 p0 = __floats2half2_rn(o[v * 8 + 0], o[v * 8 + 1]);
        __half2 p1 = __floats2half2_rn(o[v * 8 + 2], o[v * 8 + 3]);
        __half2 p2 = __floats2half2_rn(o[v * 8 + 4], o[v * 8 + 5]);
        __half2 p3 = __floats2half2_rn(o[v * 8 + 6], o[v * 8 + 7]);
        int4 pk4;
        pk4.x = *(int*)&p0; pk4.y = *(int*)&p1;
        pk4.z = *(int*)&p2; pk4.w = *(int*)&p3;
        ((int4*)((__half*)outv + (size_t)wid * dofull + c))[v] = pk4;
      }
    } else {
      float* op = (float*)outv + (size_t)wid * dofull + c;
      #pragma unroll
      for (int v = 0; v < CH / 4; ++v)
        ((float4*)op)[v] = make_float4(o[v * 4], o[v * 4 + 1],
                                       o[v * 4 + 2], o[v * 4 + 3]);
    }
  }
}

// ---------------------------------------------------------------------------
extern "C" void kernel_launch(void* const* d_in, const int* in_sizes, int n_in,
                              void* d_out, int out_size, void* d_ws, size_t ws_size,
                              hipStream_t stream) {
  const float* x   = (const float*)d_in[0];
  const int*   ei  = (const int*)d_in[1];
  const float* Wn0 = (const float*)d_in[2];
  const float* cn0 = (const float*)d_in[3];
  const float* Wr0 = (const float*)d_in[4];
  const float* cr0 = (const float*)d_in[5];
  const float* Wn1 = (const float*)d_in[6];
  const float* cn1 = (const float*)d_in[7];
  const float* Wr1 = (const float*)d_in[8];
  const float* cr1 = (const float*)d_in[9];
  const float* Wn2 = (const float*)d_in[10];
  const float* cn2 = (const float*)d_in[11];
  const float* Wr2 = (const float*)d_in[12];
  const float* cr2 = (const float*)d_in[13];
  const float* g0  = (const float*)d_in[14];
  const float* b0  = (const float*)d_in[15];
  const float* m0  = (const float*)d_in[16];
  const float* v0  = (const float*)d_in[17];
  const float* g1  = (const float*)d_in[18];
  const float* b1  = (const float*)d_in[19];
  const float* m1  = (const float*)d_in[20];
  const float* v1  = (const float*)d_in[21];

  const int* src = ei;
  const int* dst = ei + E_EDGES;

  char* p = (char*)d_ws;
  auto alloc = [&](size_t bytes) {
    char* r = p;
    p += (bytes + 255) & ~(size_t)255;
    return r;
  };
  __half*         P0      = (__half*)        alloc((size_t)N_NODES * 128 * 2);
  __half*         P1      = (__half*)        alloc((size_t)N_NODES * 128 * 2);
  __half*         A16     = (__half*)        alloc((size_t)N_NODES * 128 * 2);
  unsigned*       staging = (unsigned*)      alloc((size_t)NSB * NSUBL * SUBCAP * 4); // 8 MB
  int*            deg     = (int*)           alloc((size_t)N_NODES * 4);
  float*          denom   = (float*)         alloc((size_t)N_NODES * 4);
  int*            rowptr  = (int*)           alloc((size_t)(N_NODES + 1) * 4);
  int*            gcur    = (int*)           alloc((size_t)N_NODES * 4);
  int*            sbsum   = (int*)           alloc((size_t)NSB * 4);
  int*            sbbase  = (int*)           alloc((size_t)NSB * 4);
  int*            gc      = (int*)           alloc((size_t)(NSB * NSUBL * BSTR + 16) * 4);
  unsigned short* csrs16  = (unsigned short*)alloc((size_t)E_EDGES * 2);
  unsigned*       csrp    = (unsigned*)      alloc((size_t)E_EDGES * 4);
  __half*         WtN0    = (__half*)        alloc(128 * 128 * 2);
  __half*         WtR0    = (__half*)        alloc(128 * 128 * 2);
  __half*         WtN1    = (__half*)        alloc(128 * 128 * 2);
  __half*         WtR1    = (__half*)        alloc(128 * 128 * 2);
  __half*         WtN2    = (__half*)        alloc(64 * 128 * 2);
  __half*         WtR2    = (__half*)        alloc(64 * 128 * 2);
  float*          bias0   = (float*)         alloc(128 * 4);
  float*          bias1   = (float*)         alloc(128 * 4);
  float*          bias2   = (float*)         alloc(64 * 4);

  // fp8 Y planes (hidden layers) alias P0: xn dead after edge_weights.
  unsigned char* Y8 = (unsigned char*)P0;

  // overflow list aliases csrp (only written later by edge_weights)
  unsigned* ostage = (unsigned*)csrp;
  int*      ocnt   = gc + NSB * NSUBL * BSTR;   // covered by gc memset

  hipMemsetAsync(gc, 0, (size_t)(NSB * NSUBL * BSTR + 16) * 4, stream);

  const int node_grid = (N_NODES * 64 + 255) / 256;

  xn_norm<<<node_grid, 256, 0, stream>>>(x, P0, N_NODES);
  prep_weights<<<320, 256, 0, stream>>>(Wn0, Wr0, Wn1, Wr1, Wn2, Wr2,
                                        cn0, cr0, cn1, cr1, cn2, cr2,
                                        WtN0, WtR0, WtN1, WtR1, WtN2, WtR2,
                                        bias0, bias1, bias2);
  scatter_sb<<<SCGRID, 256, 0, stream>>>(src, dst, gc, staging, ocnt, ostage, E_EDGES);
  hist_sb<<<NSB, 256, 0, stream>>>(staging, gc, deg, sbsum, N_NODES);
  overflow_deg<<<64, 256, 0, stream>>>(ostage, ocnt, deg, sbsum);
  scan_sb<<<1, 128, 0, stream>>>(sbsum, sbbase, rowptr, N_NODES);
  rowptr_sb<<<NSB, 256, 0, stream>>>(deg, sbbase, rowptr, N_NODES);
  place_sb<<<NSB, 256, 0, stream>>>(staging, gc, rowptr, csrs16, gcur, N_NODES);
  overflow_place<<<64, 256, 0, stream>>>(ostage, ocnt, gcur, csrs16);
  edge_weights<<<node_grid, 256, 0, stream>>>(P0, rowptr, csrs16, csrp, denom, N_NODES);

  const int gemm_grid = (N_NODES + 63) / 64;

  // layer 0: H = x (f32), Y -> fp8 64-ch planes in Y8, Z -> P1, out -> A16
  gemm_dual_mfma<128, float, 1><<<gemm_grid, 256, 0, stream>>>(
      x, WtN0, WtR0, bias0, Y8, P1, N_NODES);
  for (int pass = 0; pass < 2; ++pass)
    agg_pass<true, true, true><<<node_grid, 256, 0, stream>>>(
        Y8 + (size_t)pass * N_NODES * 64, P1, rowptr, csrp, denom,
        g0, b0, m0, v0, A16, 128, pass * 64, N_NODES);

  // layer 1: H = A16 (fp16)
  gemm_dual_mfma<128, __half, 1><<<gemm_grid, 256, 0, stream>>>(
      A16, WtN1, WtR1, bias1, Y8, P1, N_NODES);
  for (int pass = 0; pass < 2; ++pass)
    agg_pass<true, true, true><<<node_grid, 256, 0, stream>>>(
        Y8 + (size_t)pass * N_NODES * 64, P1, rowptr, csrp, denom,
        g1, b1, m1, v1, A16, 128, pass * 64, N_NODES);

  // layer 2 (64-wide, fp16 planes for output precision, straight to d_out)
  gemm_dual_mfma<64, __half, 0><<<gemm_grid, 256, 0, stream>>>(
      A16, WtN2, WtR2, bias2, P0, P1, N_NODES);
  for (int pass = 0; pass < 2; ++pass)
    agg_pass<false, false, false><<<node_grid, 256, 0, stream>>>(
        P0 + (size_t)pass * N_NODES * 32, P1, rowptr, csrp, denom,
        nullptr, nullptr, nullptr, nullptr, d_out, 64, pass * 32, N_NODES);
}